// Round 7
// baseline (127.870 us; speedup 1.0000x reference)
//
#include <hip/hip_runtime.h>

#define Bn   4
#define Nn   1024
#define Mn   100
#define NB   25
#define FEAT 50
#define PIc  3.1415926f
#define RSTEP (5.5f / 24.0f)
#define INVSTEP (24.0f / 5.5f)
#define RCUT 2.75f

#define ATB  16
#define NATOMS (Bn * Nn)
#define ORDER_LEN (NATOMS + ATB)        // 4112
#define MLP_BLOCKS (ORDER_LEN / ATB)    // 257
#define TYW  122880                     // ushorts per type in wsu

#define GPB  32
#define CPG  32
#define FTHREADS 512

typedef __attribute__((ext_vector_type(8))) short bf16x8;
typedef __attribute__((ext_vector_type(4))) float f32x4;

union U16x8 { unsigned short u[8]; bf16x8 v; uint4 q; };

__device__ __forceinline__ unsigned short f2bh(float x) {
    union { float f; unsigned u; } v; v.f = x;
    unsigned r = v.u + 0x7fffu + ((v.u >> 16) & 1u);
    return (unsigned short)(r >> 16);
}
__device__ __forceinline__ float bh2f(unsigned short h) {
    union { unsigned u; float f; } v; v.u = ((unsigned)h) << 16; return v.f;
}
__device__ __forceinline__ float fast_tanh(float x) {
    float ax = fabsf(x);
    float t  = __expf(-2.0f * ax);
    float r  = (1.0f - t) * __builtin_amdgcn_rcpf(1.0f + t);
    return copysignf(r, x);
}

// wsu layout per type (ushort offsets):
// 0      WT0h [128j][64k]   8192      (fwd L0 hi)
// 8192   WT0l [128j][64k]   8192      (fwd L0 lo)
// 16384  WT1h [128j][128k] 16384
// 32768  WT1l              16384
// 49152  WT2h              16384
// 65536  WT2l              16384
// 81920  WRM2 [128i][128j] 16384      (bwd, hi only, = W2 row-major)
// 98304  WRM1              16384
// 114688 WRM0 [64f][128j]   8192

// ------------------------------------------------ wprep: transpose+copy+sort
__global__ __launch_bounds__(256) void wprep_kernel(
    const int* __restrict__ itype,
    const float* __restrict__ W0, const float* __restrict__ W1,
    const float* __restrict__ W2,
    int* __restrict__ order, unsigned short* __restrict__ wsu)
{
    const int blk = blockIdx.x;
    const int t = threadIdx.x;

    if (blk < 20) {
        // LDS tile transpose for forward layouts (hi+lo)
        __shared__ float tile[64][65];
        int ty = blk / 10, m = blk - ty * 10;
        int mat, jt, kt;
        if (m < 2)      { mat = 0; jt = m;            kt = 0; }
        else if (m < 6) { mat = 1; jt = (m - 2) >> 1; kt = (m - 2) & 1; }
        else            { mat = 2; jt = (m - 6) >> 1; kt = (m - 6) & 1; }
        const float* src = (mat == 0) ? W0 + ty * 5000
                          : (mat == 1) ? W1 + ty * 10000 : W2 + ty * 10000;
        const int Krows = (mat == 0) ? 50 : 100;
        const int Ck    = (mat == 0) ? 64 : 128;
        const int dH = ty * TYW + ((mat == 0) ? 0 : (mat == 1) ? 16384 : 49152);
        const int dL = dH + ((mat == 0) ? 8192 : 16384);
        const int j0 = jt * 64, k0 = kt * 64;
        const int rr0 = t >> 6, l = t & 63;
        #pragma unroll
        for (int i = 0; i < 16; ++i) {
            int rr = rr0 + 4 * i;
            int k = k0 + rr, j = j0 + l;
            float v = (k < Krows && j < 100) ? src[k * 100 + j] : 0.0f;
            tile[rr][l] = v;
        }
        __syncthreads();
        #pragma unroll
        for (int i = 0; i < 16; ++i) {
            int jj = rr0 + 4 * i;
            float v = tile[l][jj];
            unsigned short h = f2bh(v);
            wsu[dH + (j0 + jj) * Ck + k0 + l] = h;
            wsu[dL + (j0 + jj) * Ck + k0 + l] = f2bh(v - bh2f(h));
        }
        return;
    }
    if (blk < 340) {
        // straight copies (bwd row-major, hi only), coalesced
        int e = (blk - 20) * 256 + t;          // < 81920
        int ty = e / 40960;
        int r  = e - ty * 40960;
        float v = 0.0f; int dst;
        if (r < 16384) {            // WRM2
            int i = r >> 7, j = r & 127;
            if (i < 100 && j < 100) v = W2[ty * 10000 + i * 100 + j];
            dst = ty * TYW + 81920 + r;
        } else if (r < 32768) {     // WRM1
            int r2 = r - 16384; int i = r2 >> 7, j = r2 & 127;
            if (i < 100 && j < 100) v = W1[ty * 10000 + i * 100 + j];
            dst = ty * TYW + 98304 + r2;
        } else {                    // WRM0
            int r2 = r - 32768; int f = r2 >> 7, j = r2 & 127;
            if (f < 50 && j < 100) v = W0[ty * 5000 + f * 100 + j];
            dst = ty * TYW + 114688 + r2;
        }
        wsu[dst] = f2bh(v);
        return;
    }
    // sort block: type partition, pad each segment to ATB
    __shared__ int scan[256];
    for (int i = t; i < ORDER_LEN; i += 256) order[i] = -1;
    int tyv[16]; int c0 = 0;
    #pragma unroll
    for (int k = 0; k < 16; ++k) {
        int tt = (itype[t * 16 + k] == 8) ? 1 : 0;
        tyv[k] = tt; c0 += 1 - tt;
    }
    scan[t] = c0;
    __syncthreads();
    for (int off = 1; off < 256; off <<= 1) {
        int v = scan[t];
        int add = (t >= off) ? scan[t - off] : 0;
        __syncthreads();
        scan[t] = v + add;
        __syncthreads();
    }
    int total0 = scan[255];
    int ex0 = scan[t] - c0;
    int ex1 = 16 * t - ex0;
    int pad0 = (total0 + (ATB - 1)) & ~(ATB - 1);
    int p0 = ex0, p1 = pad0 + ex1;
    #pragma unroll
    for (int k = 0; k < 16; ++k) {
        int idx = t * 16 + k;
        if (tyv[k] == 0) order[p0++] = idx; else order[p1++] = idx;
    }
}

// ---------------------------------------------------------------- feat ----
__global__ __launch_bounds__(128) void feat_kernel(
    const int* __restrict__ itype, const int* __restrict__ nlist,
    const float* __restrict__ dR, float* __restrict__ featp)
{
    const int atom = blockIdx.x;
    const int b = atom >> 10;
    const int t = threadIdx.x;
    __shared__ float sacc[FEAT];
    if (t < FEAT) sacc[t] = 0.0f;
    __syncthreads();
    if (t < Mn) {
        float4 qv = ((const float4*)dR)[(size_t)atom * Mn + t];
        int v = nlist[(size_t)atom * Mn + t];
        if (v > 0) {
            float r = qv.x;
            if (r > 0.0f && r < 6.0f) {
                int tt = (itype[b * Nn + v - 1] == 8) ? 1 : 0;
                float cw = 0.5f * __cosf(PIc * r) + 0.5f;
                int k0 = (int)ceilf((r - 0.5f - RCUT) * INVSTEP);
                int k1 = (int)floorf((r - 0.5f + RCUT) * INVSTEP);
                k0 = max(k0, 0); k1 = min(k1, 24);
                for (int k = k0; k <= k1; ++k) {
                    float d = r - (0.5f + k * RSTEP);
                    atomicAdd(&sacc[tt * NB + k], __expf(-d * d) * cw);
                }
            }
        }
    }
    __syncthreads();
    if (t < 64) featp[(size_t)atom * 64 + t] = (t < FEAT) ? sacc[t] : 0.0f;
}

// ----------------------------------------------------------------- mlp ----
// 256 thr = 4 waves, 16 type-pure atoms. 9 stage-phases, ping-pong wlds,
// one barrier per phase, reg-prefetch of next stage during current GEMM.
// Forward layers: hi+lo (2 MFMAs/tile); backward: hi only.
#define ISSUE_N(OFFU, N4)                                                     \
    { const uint4* sp = (const uint4*)(wbase + (OFFU));                       \
      _Pragma("unroll")                                                       \
      for (int i = 0; i < (N4); ++i) wreg[i] = sp[t + 256 * i]; }

#define WRITE_WA(WBUF)                                                        \
    { _Pragma("unroll")                                                       \
      for (int i = 0; i < 4; ++i) { int q_ = t + 256 * i;                     \
        int row_ = q_ >> 3, cc_ = q_ & 7;                                     \
        *(uint4*)&wlds[WBUF][(row_ << 6) | ((cc_ ^ (row_ & 7)) << 3)] = wreg[i]; } }

#define WRITE_WB(WBUF, N4)                                                    \
    { _Pragma("unroll")                                                       \
      for (int i = 0; i < (N4); ++i) { int q_ = t + 256 * i;                  \
        int row_ = q_ >> 4, cc_ = q_ & 15;                                    \
        *(uint4*)&wlds[WBUF][(row_ << 7) | ((cc_ ^ (row_ & 7)) << 3)] = wreg[i]; } }

#define GEMM_PH(ABUF, WBUF, NKT, NS, ROWSH)                                   \
    { _Pragma("unroll")                                                       \
      for (int kt = 0; kt < (NKT); ++kt) {                                    \
        int gk = kt * 4 + q;                                                  \
        bf16x8 af = *(const bf16x8*)&aA[ABUF][(c << 7) | ((gk ^ (c & 7)) << 3)]; \
        _Pragma("unroll")                                                     \
        for (int s2 = 0; s2 < (NS); ++s2) {                                   \
            int jj = c + 16 * ((NS) * w + s2);                                \
            bf16x8 bf = *(const bf16x8*)&wlds[WBUF][(jj << (ROWSH)) | ((gk ^ (c & 7)) << 3)]; \
            acc[s2] = __builtin_amdgcn_mfma_f32_16x16x32_bf16(af, bf, acc[s2], 0, 0, 0); \
        } } }

#define WRACT(BUF, J, A, X)                                                   \
    aA[BUF][((A) << 7) | ((((J) >> 3) ^ ((A) & 7)) << 3) | ((J) & 7)] = f2bh(X)

__global__ __launch_bounds__(256) void mlp_kernel(
    const float* __restrict__ featp, const int* __restrict__ itype,
    const int* __restrict__ order, const unsigned short* __restrict__ wsu,
    const float* __restrict__ B0, const float* __restrict__ B1,
    const float* __restrict__ B2, const float* __restrict__ W3,
    const float* __restrict__ B3,
    float* __restrict__ Ei, float* __restrict__ dE)
{
    const int t = threadIdx.x;
    const int w = t >> 6;
    const int lane = t & 63;
    const int c = lane & 15, q = lane >> 4;

    __shared__ unsigned short wlds[2][16384];   // 64KB ping-pong
    __shared__ unsigned short aA[2][2048];      // 8KB
    __shared__ float fshf[16][52];
    __shared__ float dx1s[16][112];
    __shared__ float biasS[4][128];
    __shared__ float eip[4][16];
    __shared__ int aid[16];

    if (t < 16) aid[t] = order[blockIdx.x * ATB + t];
    __syncthreads();
    int first = -1;
    #pragma unroll
    for (int a = 0; a < ATB; ++a) { int v = aid[a]; if (first < 0 && v >= 0) first = v; }
    if (first < 0) return;
    const int ty = (itype[first] == 8) ? 1 : 0;
    const unsigned short* wbase = wsu + (size_t)ty * TYW;

    const int srow = t >> 4, sg = t & 15;
    const int sperm = sg ^ (srow & 7);
    uint4 wreg[8];

    // ---- prologue: issue WT0h; stage feats + biases; write WT0h; issue WT0l
    ISSUE_N(0, 4);
    {
        int v = aid[srow];
        float4 fa = {0,0,0,0}, fb = {0,0,0,0};
        if (v >= 0 && sg < 8) {
            const float4* fp = (const float4*)(featp + (size_t)v * 64 + sg * 8);
            fa = fp[0]; fb = fp[1];
        }
        U16x8 pk;
        pk.u[0]=f2bh(fa.x); pk.u[1]=f2bh(fa.y); pk.u[2]=f2bh(fa.z); pk.u[3]=f2bh(fa.w);
        pk.u[4]=f2bh(fb.x); pk.u[5]=f2bh(fb.y); pk.u[6]=f2bh(fb.z); pk.u[7]=f2bh(fb.w);
        *(uint4*)&aA[0][(srow << 7) | (sperm << 3)] = pk.q;
        int cbase = sg * 8;
        if (cbase < 52) {
            float vals[8] = {fa.x,fa.y,fa.z,fa.w,fb.x,fb.y,fb.z,fb.w};
            #pragma unroll
            for (int j7 = 0; j7 < 8; ++j7)
                if (cbase + j7 < 52) fshf[srow][cbase + j7] = vals[j7];
        }
    }
    for (int idx = t; idx < 512; idx += 256) {
        int row = idx >> 7, col = idx & 127;
        const float* s = (row == 0) ? B0 : (row == 1) ? B1 : (row == 2) ? B2 : W3;
        biasS[row][col] = (col < 100) ? s[ty * 100 + col] : 0.0f;
    }
    WRITE_WA(0);
    ISSUE_N(8192, 4);
    __syncthreads();

    f32x4 acc[2];
    float xr[2][4], h0r[2][4], h1r[2][4], h2r[2][4], dxr[2][4];

    // ---- p0: L0-hi (buf0) ----
    acc[0] = (f32x4){0,0,0,0}; acc[1] = acc[0];
    GEMM_PH(0, 0, 2, 2, 6);
    WRITE_WA(1);
    ISSUE_N(16384, 8);
    __syncthreads();

    // ---- p1: L0-lo (buf1) + epilogue L0 ----
    GEMM_PH(0, 1, 2, 2, 6);
    #pragma unroll
    for (int s = 0; s < 2; ++s) {
        int j = c + 16 * (2 * w + s);
        float bj = biasS[0][j];
        #pragma unroll
        for (int r = 0; r < 4; ++r) {
            int a = q * 4 + r;
            float z = acc[s][r] + bj;
            float h = 0.f, x = 0.f;
            if (j < 100) { h = fast_tanh(z); x = h + fshf[a][(j < 50) ? j : j - 50]; }
            h0r[s][r] = h; xr[s][r] = x;
            WRACT(1, j, a, x);
        }
    }
    WRITE_WB(0, 8);
    ISSUE_N(32768, 8);
    __syncthreads();

    // ---- p2: L1-hi (buf0, A=aA1) ----
    acc[0] = (f32x4){0,0,0,0}; acc[1] = acc[0];
    GEMM_PH(1, 0, 4, 2, 7);
    WRITE_WB(1, 8);
    ISSUE_N(49152, 8);
    __syncthreads();

    // ---- p3: L1-lo (buf1) + epilogue L1 ----
    GEMM_PH(1, 1, 4, 2, 7);
    #pragma unroll
    for (int s = 0; s < 2; ++s) {
        int j = c + 16 * (2 * w + s);
        float bj = biasS[1][j];
        #pragma unroll
        for (int r = 0; r < 4; ++r) {
            int a = q * 4 + r;
            float z = acc[s][r] + bj;
            float h = (j < 100) ? fast_tanh(z) : 0.f;
            float x = (j < 100) ? (h + xr[s][r]) : 0.f;
            h1r[s][r] = h; xr[s][r] = x;
            WRACT(0, j, a, x);
        }
    }
    WRITE_WB(0, 8);
    ISSUE_N(65536, 8);
    __syncthreads();

    // ---- p4: L2-hi (buf0, A=aA0) ----
    acc[0] = (f32x4){0,0,0,0}; acc[1] = acc[0];
    GEMM_PH(0, 0, 4, 2, 7);
    WRITE_WB(1, 8);
    ISSUE_N(81920, 8);
    __syncthreads();

    // ---- p5: L2-lo (buf1) + epilogue L2 + Ei + dz2 ----
    GEMM_PH(0, 1, 4, 2, 7);
    #pragma unroll
    for (int s = 0; s < 2; ++s) {
        int j = c + 16 * (2 * w + s);
        float bj = biasS[2][j];
        #pragma unroll
        for (int r = 0; r < 4; ++r) {
            float z = acc[s][r] + bj;
            float h = (j < 100) ? fast_tanh(z) : 0.f;
            h2r[s][r] = h;
            xr[s][r] = (j < 100) ? (h + xr[s][r]) : 0.f;   // x3
        }
    }
    {
        float p4v[4] = {0,0,0,0};
        #pragma unroll
        for (int s = 0; s < 2; ++s) {
            int j = c + 16 * (2 * w + s);
            float wv = biasS[3][j];
            #pragma unroll
            for (int r = 0; r < 4; ++r) p4v[r] += xr[s][r] * wv;
        }
        #pragma unroll
        for (int off = 1; off < 16; off <<= 1) {
            #pragma unroll
            for (int r = 0; r < 4; ++r) p4v[r] += __shfl_xor(p4v[r], off);
        }
        if (c == 0) {
            #pragma unroll
            for (int r = 0; r < 4; ++r) eip[w][q * 4 + r] = p4v[r];
        }
        #pragma unroll
        for (int s = 0; s < 2; ++s) {
            int j = c + 16 * (2 * w + s);
            float w3j = biasS[3][j];
            #pragma unroll
            for (int r = 0; r < 4; ++r) {
                int a = q * 4 + r;
                float d = w3j * (1.0f - h2r[s][r] * h2r[s][r]);
                WRACT(1, j, a, d);
            }
        }
    }
    WRITE_WB(0, 8);
    ISSUE_N(98304, 8);
    __syncthreads();
    if (t < 16) {
        int v = aid[t];
        if (v >= 0) Ei[v] = eip[0][t] + eip[1][t] + eip[2][t] + eip[3][t] + B3[ty];
    }

    // ---- p6: bwd2 (buf0=WRM2, A=aA1 dz2) ----
    acc[0] = (f32x4){0,0,0,0}; acc[1] = acc[0];
    GEMM_PH(1, 0, 4, 2, 7);
    #pragma unroll
    for (int s = 0; s < 2; ++s) {
        int i = c + 16 * (2 * w + s);
        float w3i = biasS[3][i];
        #pragma unroll
        for (int r = 0; r < 4; ++r) {
            int a = q * 4 + r;
            float dx2 = acc[s][r] + w3i;
            dxr[s][r] = dx2;
            float d = dx2 * (1.0f - h1r[s][r] * h1r[s][r]);   // dz1
            WRACT(0, i, a, d);
        }
    }
    WRITE_WB(1, 8);
    ISSUE_N(114688, 4);
    __syncthreads();

    // ---- p7: bwd1 (buf1=WRM1, A=aA0 dz1) ----
    acc[0] = (f32x4){0,0,0,0}; acc[1] = acc[0];
    GEMM_PH(0, 1, 4, 2, 7);
    #pragma unroll
    for (int s = 0; s < 2; ++s) {
        int i = c + 16 * (2 * w + s);
        #pragma unroll
        for (int r = 0; r < 4; ++r) {
            int a = q * 4 + r;
            float dx1 = dxr[s][r] + acc[s][r];
            if (i < 112) dx1s[a][i] = dx1;
            float d = dx1 * (1.0f - h0r[s][r] * h0r[s][r]);   // dz0
            WRACT(1, i, a, d);
        }
    }
    WRITE_WB(0, 4);
    __syncthreads();

    // ---- p8: bwd0 (buf0=WRM0, A=aA1 dz0) ----
    acc[0] = (f32x4){0,0,0,0};
    GEMM_PH(1, 0, 4, 1, 7);
    {
        int f = c + 16 * w;
        if (f < 50) {
            #pragma unroll
            for (int r = 0; r < 4; ++r) {
                int a = q * 4 + r;
                int v = aid[a];
                if (v >= 0) dE[(size_t)v * FEAT + f] = acc[0][r] + dx1s[a][f] + dx1s[a][f + 50];
            }
        }
    }
}

// --------------------------------------------------------------- force ----
__global__ __launch_bounds__(FTHREADS) void force_kernel(
    const int* __restrict__ itype, const int* __restrict__ nlist,
    const float* __restrict__ dR, const float* __restrict__ dE,
    float* __restrict__ partial)
{
    const int blk = blockIdx.x;
    const int b = blk / GPB;
    const int g = blk - b * GPB;
    const int t = threadIdx.x;

    __shared__ float acc[(Nn + 1) * 3];
    __shared__ float desh[CPG][FEAT];

    for (int idx = t; idx < (Nn + 1) * 3; idx += FTHREADS) acc[idx] = 0.0f;
    for (int idx = t; idx < CPG * FEAT; idx += FTHREADS)
        ((float*)desh)[idx] = dE[((size_t)(b * Nn) + g * CPG) * FEAT + idx];
    __syncthreads();

    for (int p = t; p < CPG * Mn; p += FTHREADS) {
        int cc = p / Mn, m = p - cc * Mn;
        int n = g * CPG + cc;
        size_t pair = (size_t)(b * Nn + n) * Mn + m;
        float4 qv = ((const float4*)dR)[pair];
        int v = nlist[pair];
        if (v > 0) {
            float r = qv.x;
            if (r > 0.0f && r < 6.0f) {
                int tt = (itype[b * Nn + v - 1] == 8) ? 1 : 0;
                float cw  = 0.5f * __cosf(PIc * r) + 0.5f;
                float dcw = -0.5f * PIc * __sinf(PIc * r);
                int k0 = (int)ceilf((r - 0.5f - RCUT) * INVSTEP);
                int k1 = (int)floorf((r - 0.5f + RCUT) * INVSTEP);
                k0 = max(k0, 0); k1 = min(k1, 24);
                float s = 0.0f;
                const float* de = &desh[cc][tt * NB];
                for (int k = k0; k <= k1; ++k) {
                    float d = r - (0.5f + k * RSTEP);
                    float e = __expf(-d * d);
                    s += de[k] * e * __builtin_fmaf(-2.0f * cw, d, dcw);
                }
                float inv = 1.0f / r;
                float fx = s * qv.y * inv, fy = s * qv.z * inv, fz = s * qv.w * inv;
                atomicAdd(&acc[v * 3 + 0], fx);
                atomicAdd(&acc[v * 3 + 1], fy);
                atomicAdd(&acc[v * 3 + 2], fz);
                atomicAdd(&acc[(n + 1) * 3 + 0], -fx);
                atomicAdd(&acc[(n + 1) * 3 + 1], -fy);
                atomicAdd(&acc[(n + 1) * 3 + 2], -fz);
            }
        }
    }
    __syncthreads();

    float* pout = partial + (size_t)blk * ((Nn + 1) * 3);
    for (int idx = t; idx < (Nn + 1) * 3; idx += FTHREADS) pout[idx] = acc[idx];
}

// ----------------------------------------------------- freduce (+etot) ----
__global__ __launch_bounds__(256) void freduce_kernel(
    const float* __restrict__ partial, const float* __restrict__ Ei,
    float* __restrict__ Force, float* __restrict__ Etot)
{
    if (blockIdx.x == 48) {   // etot
        const int t = threadIdx.x;
        __shared__ float red[256];
        for (int b = 0; b < Bn; ++b) {
            float s = 0.0f;
            for (int i = t; i < Nn; i += 256) s += Ei[b * Nn + i];
            red[t] = s;
            __syncthreads();
            for (int st = 128; st > 0; st >>= 1) {
                if (t < st) red[t] += red[t + st];
                __syncthreads();
            }
            if (t == 0) Etot[b] = red[0];
            __syncthreads();
        }
        return;
    }
    int idx = blockIdx.x * 256 + threadIdx.x;
    if (idx >= Bn * Nn * 3) return;
    int b = idx / (Nn * 3);
    int r = idx - b * (Nn * 3);
    int i = r / 3, ch = r - i * 3;
    float s = 0.0f;
    for (int g = 0; g < GPB; ++g)
        s += partial[((size_t)(b * GPB + g)) * ((Nn + 1) * 3) + (size_t)(i + 1) * 3 + ch];
    Force[idx] = s;
}

// -------------------------------------------------------------- launch ----
extern "C" void kernel_launch(void* const* d_in, const int* in_sizes, int n_in,
                              void* d_out, int out_size, void* d_ws, size_t ws_size,
                              hipStream_t stream)
{
    const int*   itype = (const int*)d_in[0];
    const int*   nlist = (const int*)d_in[1];
    const float* dR    = (const float*)d_in[2];
    const float* W0 = (const float*)d_in[3];  const float* B0 = (const float*)d_in[4];
    const float* W1 = (const float*)d_in[5];  const float* B1 = (const float*)d_in[6];
    const float* W2 = (const float*)d_in[7];  const float* B2 = (const float*)d_in[8];
    const float* W3 = (const float*)d_in[9];  const float* B3 = (const float*)d_in[10];

    float* out   = (float*)d_out;
    float* Etot  = out;                    // [B,1]
    float* Ei    = out + Bn;               // [B,N,1]
    float* Force = out + Bn + Bn * Nn;     // [B,N,3]

    float* featp   = (float*)d_ws;                              // NATOMS*64 f32
    float* dEp     = featp + (size_t)NATOMS * 64;               // NATOMS*50 f32
    float* partial = dEp + (size_t)NATOMS * FEAT;               // Bn*GPB*(Nn+1)*3
    int*   order   = (int*)(partial + (size_t)Bn * GPB * (Nn + 1) * 3);
    unsigned short* wsu = (unsigned short*)(order + ORDER_LEN); // 2*TYW ushorts

    wprep_kernel  <<<341, 256, 0, stream>>>(itype, W0, W1, W2, order, wsu);
    feat_kernel   <<<NATOMS, 128, 0, stream>>>(itype, nlist, dR, featp);
    mlp_kernel    <<<MLP_BLOCKS, 256, 0, stream>>>(featp, itype, order, wsu,
                                                   B0, B1, B2, W3, B3, Ei, dEp);
    force_kernel  <<<Bn * GPB, FTHREADS, 0, stream>>>(itype, nlist, dR, dEp, partial);
    freduce_kernel<<<49, 256, 0, stream>>>(partial, Ei, Force, Etot);
}

// Round 8
// 86.678 us; speedup vs baseline: 1.4752x; 1.4752x over previous
//
#include <hip/hip_runtime.h>

#define Bn   4
#define Nn   1024
#define Mn   100
#define NB   25
#define FEAT 50
#define PIc  3.1415926f
#define RSTEP (5.5f / 24.0f)

#define ATB  8                          // atoms per MLP block
#define NATOMS (Bn * Nn)
#define ORDER_LEN (NATOMS + ATB)        // 4104
#define MLP_BLOCKS (ORDER_LEN / ATB)    // 513
#define TYW  122880                     // ushorts per type in wsu

#define GPB  32
#define CPG  32
#define FTHREADS 512

typedef __attribute__((ext_vector_type(8))) short bf16x8;
typedef __attribute__((ext_vector_type(4))) float f32x4;

union U16x8 { unsigned short u[8]; bf16x8 v; uint4 q; };

__device__ __forceinline__ unsigned short f2bh(float x) {
    union { float f; unsigned u; } v; v.f = x;
    unsigned r = v.u + 0x7fffu + ((v.u >> 16) & 1u);
    return (unsigned short)(r >> 16);
}
__device__ __forceinline__ float bh2f(unsigned short h) {
    union { unsigned u; float f; } v; v.u = ((unsigned)h) << 16; return v.f;
}
__device__ __forceinline__ float fast_tanh(float x) {
    float ax = fabsf(x);
    float t  = __expf(-2.0f * ax);
    float r  = (1.0f - t) * __builtin_amdgcn_rcpf(1.0f + t);
    return copysignf(r, x);
}

// wsu layout per type (ushort offsets):
// 0      WT0h [128j][64k]   8192   (fwd L0 hi)     8192 WT0l
// 16384  WT1h [128j][128k] 16384   32768 WT1l
// 49152  WT2h             16384    65536 WT2l
// 81920  WRM2 [128i][128j] 16384   (bwd hi only)
// 98304  WRM1             16384
// 114688 WRM0 [64f][128j]  8192

// ------------------------------------------------ wprep: transpose+copy+sort
__global__ __launch_bounds__(256) void wprep_kernel(
    const int* __restrict__ itype,
    const float* __restrict__ W0, const float* __restrict__ W1,
    const float* __restrict__ W2,
    int* __restrict__ order, unsigned short* __restrict__ wsu)
{
    const int blk = blockIdx.x;
    const int t = threadIdx.x;

    if (blk < 20) {
        __shared__ float tile[64][65];
        int ty = blk / 10, m = blk - ty * 10;
        int mat, jt, kt;
        if (m < 2)      { mat = 0; jt = m;            kt = 0; }
        else if (m < 6) { mat = 1; jt = (m - 2) >> 1; kt = (m - 2) & 1; }
        else            { mat = 2; jt = (m - 6) >> 1; kt = (m - 6) & 1; }
        const float* src = (mat == 0) ? W0 + ty * 5000
                          : (mat == 1) ? W1 + ty * 10000 : W2 + ty * 10000;
        const int Krows = (mat == 0) ? 50 : 100;
        const int Ck    = (mat == 0) ? 64 : 128;
        const int dH = ty * TYW + ((mat == 0) ? 0 : (mat == 1) ? 16384 : 49152);
        const int dL = dH + ((mat == 0) ? 8192 : 16384);
        const int j0 = jt * 64, k0 = kt * 64;
        const int rr0 = t >> 6, l = t & 63;
        #pragma unroll
        for (int i = 0; i < 16; ++i) {
            int rr = rr0 + 4 * i;
            int k = k0 + rr, j = j0 + l;
            tile[rr][l] = (k < Krows && j < 100) ? src[k * 100 + j] : 0.0f;
        }
        __syncthreads();
        #pragma unroll
        for (int i = 0; i < 16; ++i) {
            int jj = rr0 + 4 * i;
            float v = tile[l][jj];
            unsigned short h = f2bh(v);
            wsu[dH + (j0 + jj) * Ck + k0 + l] = h;
            wsu[dL + (j0 + jj) * Ck + k0 + l] = f2bh(v - bh2f(h));
        }
        return;
    }
    if (blk < 340) {
        int e = (blk - 20) * 256 + t;          // < 81920
        int ty = e / 40960;
        int r  = e - ty * 40960;
        float v = 0.0f; int dst;
        if (r < 16384) {            // WRM2
            int i = r >> 7, j = r & 127;
            if (i < 100 && j < 100) v = W2[ty * 10000 + i * 100 + j];
            dst = ty * TYW + 81920 + r;
        } else if (r < 32768) {     // WRM1
            int r2 = r - 16384; int i = r2 >> 7, j = r2 & 127;
            if (i < 100 && j < 100) v = W1[ty * 10000 + i * 100 + j];
            dst = ty * TYW + 98304 + r2;
        } else {                    // WRM0
            int r2 = r - 32768; int f = r2 >> 7, j = r2 & 127;
            if (f < 50 && j < 100) v = W0[ty * 5000 + f * 100 + j];
            dst = ty * TYW + 114688 + r2;
        }
        wsu[dst] = f2bh(v);
        return;
    }
    // sort: type partition, pad each segment to ATB
    __shared__ int scan[256];
    for (int i = t; i < ORDER_LEN; i += 256) order[i] = -1;
    int tyv[16]; int c0 = 0;
    #pragma unroll
    for (int k = 0; k < 16; ++k) {
        int tt = (itype[t * 16 + k] == 8) ? 1 : 0;
        tyv[k] = tt; c0 += 1 - tt;
    }
    scan[t] = c0;
    __syncthreads();
    for (int off = 1; off < 256; off <<= 1) {
        int v = scan[t];
        int add = (t >= off) ? scan[t - off] : 0;
        __syncthreads();
        scan[t] = v + add;
        __syncthreads();
    }
    int total0 = scan[255];
    int ex0 = scan[t] - c0;
    int ex1 = 16 * t - ex0;
    int pad0 = (total0 + (ATB - 1)) & ~(ATB - 1);
    int p0 = ex0, p1 = pad0 + ex1;
    #pragma unroll
    for (int k = 0; k < 16; ++k) {
        int idx = t * 16 + k;
        if (tyv[k] == 0) order[p0++] = idx; else order[p1++] = idx;
    }
}

// ------------------------------------------------- feat (r3-style, no atomics)
__global__ __launch_bounds__(128) void feat_kernel(
    const int* __restrict__ itype, const int* __restrict__ nlist,
    const float* __restrict__ dR, float* __restrict__ featp)
{
    const int atom = blockIdx.x;
    const int b = atom >> 10;
    const int t = threadIdx.x;

    __shared__ float rsh[Mn];
    __shared__ float csh[Mn];
    __shared__ int   tsh[Mn];

    if (t < Mn) {
        float r = dR[((size_t)atom * Mn + t) * 4 + 0];
        int v = nlist[(size_t)atom * Mn + t];
        int tt = -1;
        if (v > 0) tt = (itype[b * Nn + (v - 1)] == 8) ? 1 : 0;
        if (!(r < 6.0f && r > 0.0f)) tt = -1;
        rsh[t] = r;
        csh[t] = 0.5f * __cosf(PIc * r) + 0.5f;
        tsh[t] = tt;
    }
    __syncthreads();

    if (t < 64) {
        float acc = 0.0f;
        if (t < FEAT) {
            const int tt = t / NB;
            const int k  = t - tt * NB;
            const float rk = 0.5f + k * RSTEP;
            for (int m = 0; m < Mn; ++m) {
                if (tsh[m] == tt) {
                    float d = rsh[m] - rk;
                    acc += __expf(-d * d) * csh[m];
                }
            }
        }
        featp[(size_t)atom * 64 + t] = acc;
    }
}

// ----------------------------------------------------------------- mlp ----
// 128 thr = 2 waves, 8 type-pure atoms (16-row MFMA tile, rows 8-15 pad).
// B fragments straight from L2 (bf16x8 loads); A in XOR-swizzled LDS pingpong.
#define GEMMG(ABUF, WH, WL, NKT, RW, NS, HASLO)                               \
    { _Pragma("unroll")                                                      \
      for (int kt = 0; kt < (NKT); ++kt) {                                   \
        int gk = kt * 4 + q;                                                 \
        bf16x8 af = *(const bf16x8*)&aA[ABUF][(c << 7) | ((gk ^ (c & 7)) << 3)]; \
        _Pragma("unroll")                                                    \
        for (int s2 = 0; s2 < (NS); ++s2) {                                  \
            int jj = c + 16 * ((NS) * w + s2);                               \
            int boff = jj * (RW) + kt * 32 + q * 8;                          \
            bf16x8 bh = *(const bf16x8*)((WH) + boff);                       \
            acc[s2] = __builtin_amdgcn_mfma_f32_16x16x32_bf16(af, bh, acc[s2], 0, 0, 0); \
            if (HASLO) {                                                     \
                bf16x8 bl = *(const bf16x8*)((WL) + boff);                   \
                acc[s2] = __builtin_amdgcn_mfma_f32_16x16x32_bf16(af, bl, acc[s2], 0, 0, 0); \
            }                                                                \
        } } }

#define WRACT(BUF, J, A, X)                                                   \
    aA[BUF][((A) << 7) | ((((J) >> 3) ^ ((A) & 7)) << 3) | ((J) & 7)] = f2bh(X)

__global__ __launch_bounds__(128) void mlp_kernel(
    const float* __restrict__ featp, const int* __restrict__ itype,
    const int* __restrict__ order, const unsigned short* __restrict__ wsu,
    const float* __restrict__ B0, const float* __restrict__ B1,
    const float* __restrict__ B2, const float* __restrict__ W3,
    const float* __restrict__ B3,
    float* __restrict__ Ei, float* __restrict__ dE)
{
    const int t = threadIdx.x;
    const int w = t >> 6;
    const int lane = t & 63;
    const int c = lane & 15, q = lane >> 4;

    __shared__ unsigned short aA[2][2048];      // 16x128 bf16, pingpong (8KB)
    __shared__ float fshf[16][52];
    __shared__ float dx1s[16][112];
    __shared__ float biasS[4][128];
    __shared__ float eip[2][16];
    __shared__ int aid[16];

    if (t < 16) aid[t] = (t < ATB) ? order[blockIdx.x * ATB + t] : -1;
    __syncthreads();
    int first = -1;
    #pragma unroll
    for (int a = 0; a < ATB; ++a) { int v = aid[a]; if (first < 0 && v >= 0) first = v; }
    if (first < 0) return;
    const int ty = (itype[first] == 8) ? 1 : 0;
    const unsigned short* wb = wsu + (size_t)ty * TYW;

    // stage feats (rows 0-15, zero pad) + biases
    {
        const int srow = t >> 3, sg = t & 7;
        int v = aid[srow];
        float4 fa = {0,0,0,0}, fb = {0,0,0,0};
        if (v >= 0) {
            const float4* fp = (const float4*)(featp + (size_t)v * 64 + sg * 8);
            fa = fp[0]; fb = fp[1];
        }
        U16x8 pk;
        pk.u[0]=f2bh(fa.x); pk.u[1]=f2bh(fa.y); pk.u[2]=f2bh(fa.z); pk.u[3]=f2bh(fa.w);
        pk.u[4]=f2bh(fb.x); pk.u[5]=f2bh(fb.y); pk.u[6]=f2bh(fb.z); pk.u[7]=f2bh(fb.w);
        *(uint4*)&aA[0][(srow << 7) | ((sg ^ (srow & 7)) << 3)] = pk.q;
        int cbase = sg * 8;
        if (cbase < 52) {
            float vals[8] = {fa.x,fa.y,fa.z,fa.w,fb.x,fb.y,fb.z,fb.w};
            #pragma unroll
            for (int j7 = 0; j7 < 8; ++j7)
                if (cbase + j7 < 52) fshf[srow][cbase + j7] = vals[j7];
        }
    }
    for (int idx = t; idx < 512; idx += 128) {
        int row = idx >> 7, col = idx & 127;
        const float* s = (row == 0) ? B0 : (row == 1) ? B1 : (row == 2) ? B2 : W3;
        biasS[row][col] = (col < 100) ? s[ty * 100 + col] : 0.0f;
    }
    __syncthreads();

    f32x4 acc[4];
    float xr[4][4], h0r[4][4], h1r[4][4], h2r[4][4], dxr[4][4];

    // ---- P0: L0 fwd (A=aA0 feat, W=WT0 hi+lo, K=64) -> x1 in aA1 ----
    #pragma unroll
    for (int n = 0; n < 4; ++n) acc[n] = (f32x4){0,0,0,0};
    GEMMG(0, wb + 0, wb + 8192, 2, 64, 4, 1);
    #pragma unroll
    for (int s = 0; s < 4; ++s) {
        int j = c + 16 * (4 * w + s);
        float bj = biasS[0][j];
        #pragma unroll
        for (int r = 0; r < 4; ++r) {
            int a = q * 4 + r;
            float z = acc[s][r] + bj;
            float h = 0.f, x = 0.f;
            if (j < 100) { h = fast_tanh(z); x = h + fshf[a][(j < 50) ? j : j - 50]; }
            h0r[s][r] = h; xr[s][r] = x;
            WRACT(1, j, a, x);
        }
    }
    __syncthreads();

    // ---- P1: L1 fwd (A=aA1, W=WT1 hi+lo) -> x2 in aA0 ----
    #pragma unroll
    for (int n = 0; n < 4; ++n) acc[n] = (f32x4){0,0,0,0};
    GEMMG(1, wb + 16384, wb + 32768, 4, 128, 4, 1);
    #pragma unroll
    for (int s = 0; s < 4; ++s) {
        int j = c + 16 * (4 * w + s);
        float bj = biasS[1][j];
        #pragma unroll
        for (int r = 0; r < 4; ++r) {
            int a = q * 4 + r;
            float z = acc[s][r] + bj;
            float h = (j < 100) ? fast_tanh(z) : 0.f;
            float x = (j < 100) ? (h + xr[s][r]) : 0.f;
            h1r[s][r] = h; xr[s][r] = x;
            WRACT(0, j, a, x);
        }
    }
    __syncthreads();

    // ---- P2: L2 fwd (A=aA0, W=WT2 hi+lo) -> Ei, dz2 in aA1 ----
    #pragma unroll
    for (int n = 0; n < 4; ++n) acc[n] = (f32x4){0,0,0,0};
    GEMMG(0, wb + 49152, wb + 65536, 4, 128, 4, 1);
    #pragma unroll
    for (int s = 0; s < 4; ++s) {
        int j = c + 16 * (4 * w + s);
        float bj = biasS[2][j];
        #pragma unroll
        for (int r = 0; r < 4; ++r) {
            float z = acc[s][r] + bj;
            float h = (j < 100) ? fast_tanh(z) : 0.f;
            h2r[s][r] = h;
            xr[s][r] = (j < 100) ? (h + xr[s][r]) : 0.f;   // x3
        }
    }
    {
        float p4v[4] = {0,0,0,0};
        #pragma unroll
        for (int s = 0; s < 4; ++s) {
            int j = c + 16 * (4 * w + s);
            float wv = biasS[3][j];
            #pragma unroll
            for (int r = 0; r < 4; ++r) p4v[r] += xr[s][r] * wv;
        }
        #pragma unroll
        for (int off = 1; off < 16; off <<= 1) {
            #pragma unroll
            for (int r = 0; r < 4; ++r) p4v[r] += __shfl_xor(p4v[r], off);
        }
        if (c == 0) {
            #pragma unroll
            for (int r = 0; r < 4; ++r) eip[w][q * 4 + r] = p4v[r];
        }
        #pragma unroll
        for (int s = 0; s < 4; ++s) {
            int j = c + 16 * (4 * w + s);
            float w3j = biasS[3][j];
            #pragma unroll
            for (int r = 0; r < 4; ++r) {
                int a = q * 4 + r;
                float d = w3j * (1.0f - h2r[s][r] * h2r[s][r]);
                WRACT(1, j, a, d);
            }
        }
    }
    __syncthreads();
    if (t < ATB) {
        int v = aid[t];
        if (v >= 0) Ei[v] = eip[0][t] + eip[1][t] + B3[ty];
    }

    // ---- P3: bwd2 (A=aA1 dz2, W=WRM2 hi) -> dz1 in aA0 ----
    #pragma unroll
    for (int n = 0; n < 4; ++n) acc[n] = (f32x4){0,0,0,0};
    GEMMG(1, wb + 81920, wb, 4, 128, 4, 0);
    #pragma unroll
    for (int s = 0; s < 4; ++s) {
        int i = c + 16 * (4 * w + s);
        float w3i = biasS[3][i];
        #pragma unroll
        for (int r = 0; r < 4; ++r) {
            int a = q * 4 + r;
            float dx2 = acc[s][r] + w3i;
            dxr[s][r] = dx2;
            float d = dx2 * (1.0f - h1r[s][r] * h1r[s][r]);   // dz1
            WRACT(0, i, a, d);
        }
    }
    __syncthreads();

    // ---- P4: bwd1 (A=aA0 dz1, W=WRM1 hi) -> dz0 in aA1, dx1s ----
    #pragma unroll
    for (int n = 0; n < 4; ++n) acc[n] = (f32x4){0,0,0,0};
    GEMMG(0, wb + 98304, wb, 4, 128, 4, 0);
    #pragma unroll
    for (int s = 0; s < 4; ++s) {
        int i = c + 16 * (4 * w + s);
        #pragma unroll
        for (int r = 0; r < 4; ++r) {
            int a = q * 4 + r;
            float dx1 = dxr[s][r] + acc[s][r];
            if (i < 112) dx1s[a][i] = dx1;
            float d = dx1 * (1.0f - h0r[s][r] * h0r[s][r]);   // dz0
            WRACT(1, i, a, d);
        }
    }
    __syncthreads();

    // ---- P5: bwd0 (A=aA1 dz0, W=WRM0 hi, N=64) -> dE ----
    acc[0] = (f32x4){0,0,0,0}; acc[1] = acc[0];
    GEMMG(1, wb + 114688, wb, 4, 128, 2, 0);
    #pragma unroll
    for (int s = 0; s < 2; ++s) {
        int f = c + 16 * (2 * w + s);
        if (f < 50) {
            #pragma unroll
            for (int r = 0; r < 4; ++r) {
                int a = q * 4 + r;
                int v = aid[a];
                if (v >= 0) dE[(size_t)v * FEAT + f] = acc[s][r] + dx1s[a][f] + dx1s[a][f + 50];
            }
        }
    }
}

// --------------------------------------------------------------- force ----
__global__ __launch_bounds__(FTHREADS) void force_kernel(
    const int* __restrict__ itype, const int* __restrict__ nlist,
    const float* __restrict__ dR, const float* __restrict__ dE,
    float* __restrict__ partial)
{
    const int blk = blockIdx.x;
    const int b = blk / GPB;
    const int g = blk - b * GPB;
    const int t = threadIdx.x;

    __shared__ float acc[(Nn + 1) * 3];
    __shared__ float desh[CPG][FEAT];

    for (int idx = t; idx < (Nn + 1) * 3; idx += FTHREADS) acc[idx] = 0.0f;
    for (int idx = t; idx < CPG * FEAT; idx += FTHREADS)
        ((float*)desh)[idx] = dE[((size_t)(b * Nn) + g * CPG) * FEAT + idx];
    __syncthreads();

    for (int p = t; p < CPG * Mn; p += FTHREADS) {
        int cc = p / Mn, m = p - cc * Mn;
        int n = g * CPG + cc;
        size_t pair = (size_t)(b * Nn + n) * Mn + m;
        float4 qv = ((const float4*)dR)[pair];
        int v = nlist[pair];
        if (v > 0) {
            float r = qv.x;
            if (r > 0.0f && r < 6.0f) {
                int tt = (itype[b * Nn + v - 1] == 8) ? 1 : 0;
                float cw  = 0.5f * __cosf(PIc * r) + 0.5f;
                float dcw = -0.5f * PIc * __sinf(PIc * r);
                float s = 0.0f;
                const float* de = &desh[cc][tt * NB];
                #pragma unroll
                for (int k = 0; k < NB; ++k) {
                    float d = r - (0.5f + k * RSTEP);
                    float e = __expf(-d * d);
                    s += de[k] * e * __builtin_fmaf(-2.0f * cw, d, dcw);
                }
                float inv = 1.0f / r;
                float fx = s * qv.y * inv, fy = s * qv.z * inv, fz = s * qv.w * inv;
                atomicAdd(&acc[v * 3 + 0], fx);
                atomicAdd(&acc[v * 3 + 1], fy);
                atomicAdd(&acc[v * 3 + 2], fz);
                atomicAdd(&acc[(n + 1) * 3 + 0], -fx);
                atomicAdd(&acc[(n + 1) * 3 + 1], -fy);
                atomicAdd(&acc[(n + 1) * 3 + 2], -fz);
            }
        }
    }
    __syncthreads();

    float* pout = partial + (size_t)blk * ((Nn + 1) * 3);
    for (int idx = t; idx < (Nn + 1) * 3; idx += FTHREADS) pout[idx] = acc[idx];
}

// ----------------------------------------------------- freduce (+etot) ----
__global__ __launch_bounds__(256) void freduce_kernel(
    const float* __restrict__ partial, const float* __restrict__ Ei,
    float* __restrict__ Force, float* __restrict__ Etot)
{
    if (blockIdx.x == 48) {   // etot
        const int t = threadIdx.x;
        __shared__ float red[256];
        for (int b = 0; b < Bn; ++b) {
            float s = 0.0f;
            for (int i = t; i < Nn; i += 256) s += Ei[b * Nn + i];
            red[t] = s;
            __syncthreads();
            for (int st = 128; st > 0; st >>= 1) {
                if (t < st) red[t] += red[t + st];
                __syncthreads();
            }
            if (t == 0) Etot[b] = red[0];
            __syncthreads();
        }
        return;
    }
    int idx = blockIdx.x * 256 + threadIdx.x;
    if (idx >= Bn * Nn * 3) return;
    int b = idx / (Nn * 3);
    int r = idx - b * (Nn * 3);
    int i = r / 3, ch = r - i * 3;
    float s = 0.0f;
    for (int g = 0; g < GPB; ++g)
        s += partial[((size_t)(b * GPB + g)) * ((Nn + 1) * 3) + (size_t)(i + 1) * 3 + ch];
    Force[idx] = s;
}

// -------------------------------------------------------------- launch ----
extern "C" void kernel_launch(void* const* d_in, const int* in_sizes, int n_in,
                              void* d_out, int out_size, void* d_ws, size_t ws_size,
                              hipStream_t stream)
{
    const int*   itype = (const int*)d_in[0];
    const int*   nlist = (const int*)d_in[1];
    const float* dR    = (const float*)d_in[2];
    const float* W0 = (const float*)d_in[3];  const float* B0 = (const float*)d_in[4];
    const float* W1 = (const float*)d_in[5];  const float* B1 = (const float*)d_in[6];
    const float* W2 = (const float*)d_in[7];  const float* B2 = (const float*)d_in[8];
    const float* W3 = (const float*)d_in[9];  const float* B3 = (const float*)d_in[10];

    float* out   = (float*)d_out;
    float* Etot  = out;                    // [B,1]
    float* Ei    = out + Bn;               // [B,N,1]
    float* Force = out + Bn + Bn * Nn;     // [B,N,3]

    float* featp   = (float*)d_ws;                              // NATOMS*64 f32
    float* dEp     = featp + (size_t)NATOMS * 64;               // NATOMS*50 f32
    float* partial = dEp + (size_t)NATOMS * FEAT;               // Bn*GPB*(Nn+1)*3
    int*   order   = (int*)(partial + (size_t)Bn * GPB * (Nn + 1) * 3);
    unsigned short* wsu = (unsigned short*)(order + ORDER_LEN); // 2*TYW ushorts

    wprep_kernel  <<<341, 256, 0, stream>>>(itype, W0, W1, W2, order, wsu);
    feat_kernel   <<<NATOMS, 128, 0, stream>>>(itype, nlist, dR, featp);
    mlp_kernel    <<<MLP_BLOCKS, 128, 0, stream>>>(featp, itype, order, wsu,
                                                   B0, B1, B2, W3, B3, Ei, dEp);
    force_kernel  <<<Bn * GPB, FTHREADS, 0, stream>>>(itype, nlist, dR, dEp, partial);
    freduce_kernel<<<49, 256, 0, stream>>>(partial, Ei, Force, Etot);
}

// Round 9
// 85.086 us; speedup vs baseline: 1.5028x; 1.0187x over previous
//
#include <hip/hip_runtime.h>

#define Bn   4
#define Nn   1024
#define Mn   100
#define NB   25
#define FEAT 50
#define PIc  3.1415926f
#define RSTEP (5.5f / 24.0f)

#define ATB  8                          // atoms per MLP block
#define NATOMS (Bn * Nn)
#define ORDER_LEN (NATOMS + ATB)        // 4104
#define MLP_BLOCKS (ORDER_LEN / ATB)    // 513
#define TYW  122880                     // ushorts per type in wsu

#define GPB  32
#define CPG  32
#define FTHREADS 512

typedef __attribute__((ext_vector_type(8))) short bf16x8;
typedef __attribute__((ext_vector_type(4))) float f32x4;

union U16x8 { unsigned short u[8]; bf16x8 v; uint4 q; };

__device__ __forceinline__ unsigned short f2bh(float x) {
    union { float f; unsigned u; } v; v.f = x;
    unsigned r = v.u + 0x7fffu + ((v.u >> 16) & 1u);
    return (unsigned short)(r >> 16);
}
__device__ __forceinline__ float bh2f(unsigned short h) {
    union { unsigned u; float f; } v; v.u = ((unsigned)h) << 16; return v.f;
}
__device__ __forceinline__ float fast_tanh(float x) {
    float ax = fabsf(x);
    float t  = __expf(-2.0f * ax);
    float r  = (1.0f - t) * __builtin_amdgcn_rcpf(1.0f + t);
    return copysignf(r, x);
}

// wsu layout per type (ushort offsets):
// 0      WT0h [128j][64k]   8192   (fwd L0 hi)     8192 WT0l
// 16384  WT1h [128j][128k] 16384   32768 WT1l
// 49152  WT2h             16384    65536 WT2l
// 81920  WRM2 [128i][128j] 16384   (bwd hi only)
// 98304  WRM1             16384
// 114688 WRM0 [64f][128j]  8192

// ------------------------------------------------ wprep: transpose+copy+sort
__global__ __launch_bounds__(256) void wprep_kernel(
    const int* __restrict__ itype,
    const float* __restrict__ W0, const float* __restrict__ W1,
    const float* __restrict__ W2,
    int* __restrict__ order, unsigned short* __restrict__ wsu)
{
    const int blk = blockIdx.x;
    const int t = threadIdx.x;

    if (blk < 20) {
        __shared__ float tile[64][65];
        int ty = blk / 10, m = blk - ty * 10;
        int mat, jt, kt;
        if (m < 2)      { mat = 0; jt = m;            kt = 0; }
        else if (m < 6) { mat = 1; jt = (m - 2) >> 1; kt = (m - 2) & 1; }
        else            { mat = 2; jt = (m - 6) >> 1; kt = (m - 6) & 1; }
        const float* src = (mat == 0) ? W0 + ty * 5000
                          : (mat == 1) ? W1 + ty * 10000 : W2 + ty * 10000;
        const int Krows = (mat == 0) ? 50 : 100;
        const int Ck    = (mat == 0) ? 64 : 128;
        const int dH = ty * TYW + ((mat == 0) ? 0 : (mat == 1) ? 16384 : 49152);
        const int dL = dH + ((mat == 0) ? 8192 : 16384);
        const int j0 = jt * 64, k0 = kt * 64;
        const int rr0 = t >> 6, l = t & 63;
        #pragma unroll
        for (int i = 0; i < 16; ++i) {
            int rr = rr0 + 4 * i;
            int k = k0 + rr, j = j0 + l;
            tile[rr][l] = (k < Krows && j < 100) ? src[k * 100 + j] : 0.0f;
        }
        __syncthreads();
        #pragma unroll
        for (int i = 0; i < 16; ++i) {
            int jj = rr0 + 4 * i;
            float v = tile[l][jj];
            unsigned short h = f2bh(v);
            wsu[dH + (j0 + jj) * Ck + k0 + l] = h;
            wsu[dL + (j0 + jj) * Ck + k0 + l] = f2bh(v - bh2f(h));
        }
        return;
    }
    if (blk < 340) {
        int e = (blk - 20) * 256 + t;          // < 81920
        int ty = e / 40960;
        int r  = e - ty * 40960;
        float v = 0.0f; int dst;
        if (r < 16384) {            // WRM2
            int i = r >> 7, j = r & 127;
            if (i < 100 && j < 100) v = W2[ty * 10000 + i * 100 + j];
            dst = ty * TYW + 81920 + r;
        } else if (r < 32768) {     // WRM1
            int r2 = r - 16384; int i = r2 >> 7, j = r2 & 127;
            if (i < 100 && j < 100) v = W1[ty * 10000 + i * 100 + j];
            dst = ty * TYW + 98304 + r2;
        } else {                    // WRM0
            int r2 = r - 32768; int f = r2 >> 7, j = r2 & 127;
            if (f < 50 && j < 100) v = W0[ty * 5000 + f * 100 + j];
            dst = ty * TYW + 114688 + r2;
        }
        wsu[dst] = f2bh(v);
        return;
    }
    // sort: type partition, pad each segment to ATB
    __shared__ int scan[256];
    for (int i = t; i < ORDER_LEN; i += 256) order[i] = -1;
    int tyv[16]; int c0 = 0;
    #pragma unroll
    for (int k = 0; k < 16; ++k) {
        int tt = (itype[t * 16 + k] == 8) ? 1 : 0;
        tyv[k] = tt; c0 += 1 - tt;
    }
    scan[t] = c0;
    __syncthreads();
    for (int off = 1; off < 256; off <<= 1) {
        int v = scan[t];
        int add = (t >= off) ? scan[t - off] : 0;
        __syncthreads();
        scan[t] = v + add;
        __syncthreads();
    }
    int total0 = scan[255];
    int ex0 = scan[t] - c0;
    int ex1 = 16 * t - ex0;
    int pad0 = (total0 + (ATB - 1)) & ~(ATB - 1);
    int p0 = ex0, p1 = pad0 + ex1;
    #pragma unroll
    for (int k = 0; k < 16; ++k) {
        int idx = t * 16 + k;
        if (tyv[k] == 0) order[p0++] = idx; else order[p1++] = idx;
    }
}

// ------------------------------------------------- feat (r3-style, no atomics)
__global__ __launch_bounds__(128) void feat_kernel(
    const int* __restrict__ itype, const int* __restrict__ nlist,
    const float* __restrict__ dR, float* __restrict__ featp)
{
    const int atom = blockIdx.x;
    const int b = atom >> 10;
    const int t = threadIdx.x;

    __shared__ float rsh[Mn];
    __shared__ float csh[Mn];
    __shared__ int   tsh[Mn];

    if (t < Mn) {
        float4 qv = ((const float4*)dR)[(size_t)atom * Mn + t];
        float r = qv.x;
        int v = nlist[(size_t)atom * Mn + t];
        int tt = -1;
        if (v > 0) tt = (itype[b * Nn + (v - 1)] == 8) ? 1 : 0;
        if (!(r < 6.0f && r > 0.0f)) tt = -1;
        rsh[t] = r;
        csh[t] = 0.5f * __cosf(PIc * r) + 0.5f;
        tsh[t] = tt;
    }
    __syncthreads();

    if (t < 64) {
        float acc = 0.0f;
        if (t < FEAT) {
            const int tt = t / NB;
            const int k  = t - tt * NB;
            const float rk = 0.5f + k * RSTEP;
            for (int m = 0; m < Mn; ++m) {
                if (tsh[m] == tt) {
                    float d = rsh[m] - rk;
                    acc += __expf(-d * d) * csh[m];
                }
            }
        }
        featp[(size_t)atom * 64 + t] = acc;
    }
}

// ----------------------------------------------------------------- mlp ----
// 128 thr = 2 waves, 8 type-pure atoms (16-row MFMA tile, rows 8-15 pad).
// All A/B fragments of a phase reg-staged up-front (static arrays, full
// unroll -> registers), then the MFMA chain; hi/lo in separate acc chains.
#define GEMMG(ABUF, WH, WL, NKT, RW, NS, HASLO)                               \
    { bf16x8 afr_[4]; bf16x8 bhr_[4][4]; bf16x8 blr_[4][4];                   \
      _Pragma("unroll")                                                       \
      for (int kt = 0; kt < (NKT); ++kt) {                                    \
        int gk = kt * 4 + q;                                                  \
        afr_[kt] = *(const bf16x8*)&aA[ABUF][(c << 7) | ((gk ^ (c & 7)) << 3)]; \
        _Pragma("unroll")                                                     \
        for (int s2 = 0; s2 < (NS); ++s2) {                                   \
            int jj = c + 16 * ((NS) * w + s2);                                \
            int boff = jj * (RW) + kt * 32 + q * 8;                           \
            bhr_[kt][s2] = *(const bf16x8*)((WH) + boff);                     \
            if (HASLO) blr_[kt][s2] = *(const bf16x8*)((WL) + boff);          \
        } }                                                                   \
      _Pragma("unroll")                                                       \
      for (int kt = 0; kt < (NKT); ++kt) {                                    \
        _Pragma("unroll")                                                     \
        for (int s2 = 0; s2 < (NS); ++s2) {                                   \
            acc[s2] = __builtin_amdgcn_mfma_f32_16x16x32_bf16(afr_[kt], bhr_[kt][s2], acc[s2], 0, 0, 0); \
            if (HASLO)                                                        \
              accl[s2] = __builtin_amdgcn_mfma_f32_16x16x32_bf16(afr_[kt], blr_[kt][s2], accl[s2], 0, 0, 0); \
        } } }

#define ZACC() { _Pragma("unroll") for (int n = 0; n < 4; ++n) { acc[n] = (f32x4){0,0,0,0}; accl[n] = (f32x4){0,0,0,0}; } }

#define WRACT(BUF, J, A, X)                                                   \
    aA[BUF][((A) << 7) | ((((J) >> 3) ^ ((A) & 7)) << 3) | ((J) & 7)] = f2bh(X)

__global__ __launch_bounds__(128, 1) void mlp_kernel(
    const float* __restrict__ featp, const int* __restrict__ itype,
    const int* __restrict__ order, const unsigned short* __restrict__ wsu,
    const float* __restrict__ B0, const float* __restrict__ B1,
    const float* __restrict__ B2, const float* __restrict__ W3,
    const float* __restrict__ B3,
    float* __restrict__ Ei, float* __restrict__ dE)
{
    const int t = threadIdx.x;
    const int w = t >> 6;
    const int lane = t & 63;
    const int c = lane & 15, q = lane >> 4;

    __shared__ unsigned short aA[2][2048];      // 16x128 bf16, pingpong (8KB)
    __shared__ float fshf[16][52];
    __shared__ float dx1s[16][112];
    __shared__ float biasS[4][128];
    __shared__ float eip[2][16];
    __shared__ int aid[16];

    if (t < 16) aid[t] = (t < ATB) ? order[blockIdx.x * ATB + t] : -1;
    __syncthreads();
    int first = -1;
    #pragma unroll
    for (int a = 0; a < ATB; ++a) { int v = aid[a]; if (first < 0 && v >= 0) first = v; }
    if (first < 0) return;
    const int ty = (itype[first] == 8) ? 1 : 0;
    const unsigned short* wb = wsu + (size_t)ty * TYW;

    // stage feats (rows 0-15, zero pad) + biases
    {
        const int srow = t >> 3, sg = t & 7;
        int v = aid[srow];
        float4 fa = {0,0,0,0}, fb = {0,0,0,0};
        if (v >= 0) {
            const float4* fp = (const float4*)(featp + (size_t)v * 64 + sg * 8);
            fa = fp[0]; fb = fp[1];
        }
        U16x8 pk;
        pk.u[0]=f2bh(fa.x); pk.u[1]=f2bh(fa.y); pk.u[2]=f2bh(fa.z); pk.u[3]=f2bh(fa.w);
        pk.u[4]=f2bh(fb.x); pk.u[5]=f2bh(fb.y); pk.u[6]=f2bh(fb.z); pk.u[7]=f2bh(fb.w);
        *(uint4*)&aA[0][(srow << 7) | ((sg ^ (srow & 7)) << 3)] = pk.q;
        int cbase = sg * 8;
        if (cbase < 52) {
            float vals[8] = {fa.x,fa.y,fa.z,fa.w,fb.x,fb.y,fb.z,fb.w};
            #pragma unroll
            for (int j7 = 0; j7 < 8; ++j7)
                if (cbase + j7 < 52) fshf[srow][cbase + j7] = vals[j7];
        }
    }
    for (int idx = t; idx < 512; idx += 128) {
        int row = idx >> 7, col = idx & 127;
        const float* s = (row == 0) ? B0 : (row == 1) ? B1 : (row == 2) ? B2 : W3;
        biasS[row][col] = (col < 100) ? s[ty * 100 + col] : 0.0f;
    }
    __syncthreads();

    f32x4 acc[4], accl[4];
    float xr[4][4], h0r[4][4], h1r[4][4], h2r[4][4], dxr[4][4];

    // ---- P0: L0 fwd (A=aA0 feat, W=WT0 hi+lo, K=64) -> x1 in aA1 ----
    ZACC();
    GEMMG(0, wb + 0, wb + 8192, 2, 64, 4, 1);
    #pragma unroll
    for (int s = 0; s < 4; ++s) {
        int j = c + 16 * (4 * w + s);
        float bj = biasS[0][j];
        #pragma unroll
        for (int r = 0; r < 4; ++r) {
            int a = q * 4 + r;
            float z = acc[s][r] + accl[s][r] + bj;
            float h = 0.f, x = 0.f;
            if (j < 100) { h = fast_tanh(z); x = h + fshf[a][(j < 50) ? j : j - 50]; }
            h0r[s][r] = h; xr[s][r] = x;
            WRACT(1, j, a, x);
        }
    }
    __syncthreads();

    // ---- P1: L1 fwd (A=aA1, W=WT1 hi+lo) -> x2 in aA0 ----
    ZACC();
    GEMMG(1, wb + 16384, wb + 32768, 4, 128, 4, 1);
    #pragma unroll
    for (int s = 0; s < 4; ++s) {
        int j = c + 16 * (4 * w + s);
        float bj = biasS[1][j];
        #pragma unroll
        for (int r = 0; r < 4; ++r) {
            int a = q * 4 + r;
            float z = acc[s][r] + accl[s][r] + bj;
            float h = (j < 100) ? fast_tanh(z) : 0.f;
            float x = (j < 100) ? (h + xr[s][r]) : 0.f;
            h1r[s][r] = h; xr[s][r] = x;
            WRACT(0, j, a, x);
        }
    }
    __syncthreads();

    // ---- P2: L2 fwd (A=aA0, W=WT2 hi+lo) -> Ei, dz2 in aA1 ----
    ZACC();
    GEMMG(0, wb + 49152, wb + 65536, 4, 128, 4, 1);
    #pragma unroll
    for (int s = 0; s < 4; ++s) {
        int j = c + 16 * (4 * w + s);
        float bj = biasS[2][j];
        #pragma unroll
        for (int r = 0; r < 4; ++r) {
            float z = acc[s][r] + accl[s][r] + bj;
            float h = (j < 100) ? fast_tanh(z) : 0.f;
            h2r[s][r] = h;
            xr[s][r] = (j < 100) ? (h + xr[s][r]) : 0.f;   // x3
        }
    }
    {
        float p4v[4] = {0,0,0,0};
        #pragma unroll
        for (int s = 0; s < 4; ++s) {
            int j = c + 16 * (4 * w + s);
            float wv = biasS[3][j];
            #pragma unroll
            for (int r = 0; r < 4; ++r) p4v[r] += xr[s][r] * wv;
        }
        #pragma unroll
        for (int off = 1; off < 16; off <<= 1) {
            #pragma unroll
            for (int r = 0; r < 4; ++r) p4v[r] += __shfl_xor(p4v[r], off);
        }
        if (c == 0) {
            #pragma unroll
            for (int r = 0; r < 4; ++r) eip[w][q * 4 + r] = p4v[r];
        }
        #pragma unroll
        for (int s = 0; s < 4; ++s) {
            int j = c + 16 * (4 * w + s);
            float w3j = biasS[3][j];
            #pragma unroll
            for (int r = 0; r < 4; ++r) {
                int a = q * 4 + r;
                float d = w3j * (1.0f - h2r[s][r] * h2r[s][r]);
                WRACT(1, j, a, d);
            }
        }
    }
    __syncthreads();
    if (t < ATB) {
        int v = aid[t];
        if (v >= 0) Ei[v] = eip[0][t] + eip[1][t] + B3[ty];
    }

    // ---- P3: bwd2 (A=aA1 dz2, W=WRM2 hi) -> dz1 in aA0 ----
    ZACC();
    GEMMG(1, wb + 81920, wb, 4, 128, 4, 0);
    #pragma unroll
    for (int s = 0; s < 4; ++s) {
        int i = c + 16 * (4 * w + s);
        float w3i = biasS[3][i];
        #pragma unroll
        for (int r = 0; r < 4; ++r) {
            int a = q * 4 + r;
            float dx2 = acc[s][r] + w3i;
            dxr[s][r] = dx2;
            float d = dx2 * (1.0f - h1r[s][r] * h1r[s][r]);   // dz1
            WRACT(0, i, a, d);
        }
    }
    __syncthreads();

    // ---- P4: bwd1 (A=aA0 dz1, W=WRM1 hi) -> dz0 in aA1, dx1s ----
    ZACC();
    GEMMG(0, wb + 98304, wb, 4, 128, 4, 0);
    #pragma unroll
    for (int s = 0; s < 4; ++s) {
        int i = c + 16 * (4 * w + s);
        #pragma unroll
        for (int r = 0; r < 4; ++r) {
            int a = q * 4 + r;
            float dx1 = dxr[s][r] + acc[s][r];
            if (i < 112) dx1s[a][i] = dx1;
            float d = dx1 * (1.0f - h0r[s][r] * h0r[s][r]);   // dz0
            WRACT(1, i, a, d);
        }
    }
    __syncthreads();

    // ---- P5: bwd0 (A=aA1 dz0, W=WRM0 hi, N=64) -> dE ----
    ZACC();
    GEMMG(1, wb + 114688, wb, 4, 128, 2, 0);
    #pragma unroll
    for (int s = 0; s < 2; ++s) {
        int f = c + 16 * (2 * w + s);
        if (f < 50) {
            #pragma unroll
            for (int r = 0; r < 4; ++r) {
                int a = q * 4 + r;
                int v = aid[a];
                if (v >= 0) dE[(size_t)v * FEAT + f] = acc[s][r] + dx1s[a][f] + dx1s[a][f + 50];
            }
        }
    }
}

// --------------------------------------------------------------- force ----
__global__ __launch_bounds__(FTHREADS) void force_kernel(
    const int* __restrict__ itype, const int* __restrict__ nlist,
    const float* __restrict__ dR, const float* __restrict__ dE,
    float* __restrict__ partial)
{
    const int blk = blockIdx.x;
    const int b = blk / GPB;
    const int g = blk - b * GPB;
    const int t = threadIdx.x;

    __shared__ float acc[(Nn + 1) * 3];
    __shared__ float desh[CPG][FEAT];

    for (int idx = t; idx < (Nn + 1) * 3; idx += FTHREADS) acc[idx] = 0.0f;
    for (int idx = t; idx < CPG * FEAT; idx += FTHREADS)
        ((float*)desh)[idx] = dE[((size_t)(b * Nn) + g * CPG) * FEAT + idx];
    __syncthreads();

    for (int p = t; p < CPG * Mn; p += FTHREADS) {
        int cc = p / Mn, m = p - cc * Mn;
        int n = g * CPG + cc;
        size_t pair = (size_t)(b * Nn + n) * Mn + m;
        float4 qv = ((const float4*)dR)[pair];
        int v = nlist[pair];
        if (v > 0) {
            float r = qv.x;
            if (r > 0.0f && r < 6.0f) {
                int tt = (itype[b * Nn + v - 1] == 8) ? 1 : 0;
                float cw  = 0.5f * __cosf(PIc * r) + 0.5f;
                float dcw = -0.5f * PIc * __sinf(PIc * r);
                float s = 0.0f;
                const float* de = &desh[cc][tt * NB];
                #pragma unroll
                for (int k = 0; k < NB; ++k) {
                    float d = r - (0.5f + k * RSTEP);
                    float e = __expf(-d * d);
                    s += de[k] * e * __builtin_fmaf(-2.0f * cw, d, dcw);
                }
                float inv = 1.0f / r;
                float fx = s * qv.y * inv, fy = s * qv.z * inv, fz = s * qv.w * inv;
                atomicAdd(&acc[v * 3 + 0], fx);
                atomicAdd(&acc[v * 3 + 1], fy);
                atomicAdd(&acc[v * 3 + 2], fz);
                atomicAdd(&acc[(n + 1) * 3 + 0], -fx);
                atomicAdd(&acc[(n + 1) * 3 + 1], -fy);
                atomicAdd(&acc[(n + 1) * 3 + 2], -fz);
            }
        }
    }
    __syncthreads();

    float* pout = partial + (size_t)blk * ((Nn + 1) * 3);
    for (int idx = t; idx < (Nn + 1) * 3; idx += FTHREADS) pout[idx] = acc[idx];
}

// ----------------------------------------------------- freduce (+etot) ----
__global__ __launch_bounds__(256) void freduce_kernel(
    const float* __restrict__ partial, const float* __restrict__ Ei,
    float* __restrict__ Force, float* __restrict__ Etot)
{
    if (blockIdx.x == 48) {   // etot
        const int t = threadIdx.x;
        __shared__ float red[256];
        for (int b = 0; b < Bn; ++b) {
            float s = 0.0f;
            for (int i = t; i < Nn; i += 256) s += Ei[b * Nn + i];
            red[t] = s;
            __syncthreads();
            for (int st = 128; st > 0; st >>= 1) {
                if (t < st) red[t] += red[t + st];
                __syncthreads();
            }
            if (t == 0) Etot[b] = red[0];
            __syncthreads();
        }
        return;
    }
    int idx = blockIdx.x * 256 + threadIdx.x;
    if (idx >= Bn * Nn * 3) return;
    int b = idx / (Nn * 3);
    int r = idx - b * (Nn * 3);
    int i = r / 3, ch = r - i * 3;
    float s = 0.0f;
    for (int g = 0; g < GPB; ++g)
        s += partial[((size_t)(b * GPB + g)) * ((Nn + 1) * 3) + (size_t)(i + 1) * 3 + ch];
    Force[idx] = s;
}

// -------------------------------------------------------------- launch ----
extern "C" void kernel_launch(void* const* d_in, const int* in_sizes, int n_in,
                              void* d_out, int out_size, void* d_ws, size_t ws_size,
                              hipStream_t stream)
{
    const int*   itype = (const int*)d_in[0];
    const int*   nlist = (const int*)d_in[1];
    const float* dR    = (const float*)d_in[2];
    const float* W0 = (const float*)d_in[3];  const float* B0 = (const float*)d_in[4];
    const float* W1 = (const float*)d_in[5];  const float* B1 = (const float*)d_in[6];
    const float* W2 = (const float*)d_in[7];  const float* B2 = (const float*)d_in[8];
    const float* W3 = (const float*)d_in[9];  const float* B3 = (const float*)d_in[10];

    float* out   = (float*)d_out;
    float* Etot  = out;                    // [B,1]
    float* Ei    = out + Bn;               // [B,N,1]
    float* Force = out + Bn + Bn * Nn;     // [B,N,3]

    float* featp   = (float*)d_ws;                              // NATOMS*64 f32
    float* dEp     = featp + (size_t)NATOMS * 64;               // NATOMS*50 f32
    float* partial = dEp + (size_t)NATOMS * FEAT;               // Bn*GPB*(Nn+1)*3
    int*   order   = (int*)(partial + (size_t)Bn * GPB * (Nn + 1) * 3);
    unsigned short* wsu = (unsigned short*)(order + ORDER_LEN); // 2*TYW ushorts

    wprep_kernel  <<<341, 256, 0, stream>>>(itype, W0, W1, W2, order, wsu);
    feat_kernel   <<<NATOMS, 128, 0, stream>>>(itype, nlist, dR, featp);
    mlp_kernel    <<<MLP_BLOCKS, 128, 0, stream>>>(featp, itype, order, wsu,
                                                   B0, B1, B2, W3, B3, Ei, dEp);
    force_kernel  <<<Bn * GPB, FTHREADS, 0, stream>>>(itype, nlist, dR, dEp, partial);
    freduce_kernel<<<49, 256, 0, stream>>>(partial, Ei, Force, Etot);
}

// Round 10
// 71.068 us; speedup vs baseline: 1.7993x; 1.1972x over previous
//
#include <hip/hip_runtime.h>

#define Bn   4
#define Nn   1024
#define Mn   100
#define NB   25
#define FEAT 50
#define PIc  3.1415926f
#define RSTEP (5.5f / 24.0f)

#define ATB  8                          // atoms per MLP block
#define NATOMS (Bn * Nn)
#define ORDER_LEN (NATOMS + ATB)        // 4104
#define MLP_BLOCKS (ORDER_LEN / ATB)    // 513
#define TYW  122880                     // ushorts per type in wsu

#define GPB  64
#define CPG  16
#define FTHREADS 512

typedef __attribute__((ext_vector_type(8))) short bf16x8;
typedef __attribute__((ext_vector_type(4))) float f32x4;

union U16x8 { unsigned short u[8]; bf16x8 v; uint4 q; };

__device__ __forceinline__ unsigned short f2bh(float x) {
    union { float f; unsigned u; } v; v.f = x;
    unsigned r = v.u + 0x7fffu + ((v.u >> 16) & 1u);
    return (unsigned short)(r >> 16);
}
__device__ __forceinline__ float bh2f(unsigned short h) {
    union { unsigned u; float f; } v; v.u = ((unsigned)h) << 16; return v.f;
}
__device__ __forceinline__ float fast_tanh(float x) {
    float ax = fabsf(x);
    float t  = __expf(-2.0f * ax);
    float r  = (1.0f - t) * __builtin_amdgcn_rcpf(1.0f + t);
    return copysignf(r, x);
}

// wsu layout per type (ushort offsets):
// 0      WT0h [128j][64k]   8192   (fwd L0 hi)     8192 WT0l
// 16384  WT1h [128j][128k] 16384   32768 WT1l
// 49152  WT2h             16384    65536 WT2l
// 81920  WRM2 [128i][128j] 16384   (bwd hi only)
// 98304  WRM1             16384
// 114688 WRM0 [64f][128j]  8192

// ------------------------------------------------ wprep: transpose+copy+sort
__global__ __launch_bounds__(256) void wprep_kernel(
    const int* __restrict__ itype,
    const float* __restrict__ W0, const float* __restrict__ W1,
    const float* __restrict__ W2,
    int* __restrict__ order, unsigned short* __restrict__ wsu)
{
    const int blk = blockIdx.x;
    const int t = threadIdx.x;

    if (blk < 20) {
        __shared__ float tile[64][65];
        int ty = blk / 10, m = blk - ty * 10;
        int mat, jt, kt;
        if (m < 2)      { mat = 0; jt = m;            kt = 0; }
        else if (m < 6) { mat = 1; jt = (m - 2) >> 1; kt = (m - 2) & 1; }
        else            { mat = 2; jt = (m - 6) >> 1; kt = (m - 6) & 1; }
        const float* src = (mat == 0) ? W0 + ty * 5000
                          : (mat == 1) ? W1 + ty * 10000 : W2 + ty * 10000;
        const int Krows = (mat == 0) ? 50 : 100;
        const int Ck    = (mat == 0) ? 64 : 128;
        const int dH = ty * TYW + ((mat == 0) ? 0 : (mat == 1) ? 16384 : 49152);
        const int dL = dH + ((mat == 0) ? 8192 : 16384);
        const int j0 = jt * 64, k0 = kt * 64;
        const int rr0 = t >> 6, l = t & 63;
        #pragma unroll
        for (int i = 0; i < 16; ++i) {
            int rr = rr0 + 4 * i;
            int k = k0 + rr, j = j0 + l;
            tile[rr][l] = (k < Krows && j < 100) ? src[k * 100 + j] : 0.0f;
        }
        __syncthreads();
        #pragma unroll
        for (int i = 0; i < 16; ++i) {
            int jj = rr0 + 4 * i;
            float v = tile[l][jj];
            unsigned short h = f2bh(v);
            wsu[dH + (j0 + jj) * Ck + k0 + l] = h;
            wsu[dL + (j0 + jj) * Ck + k0 + l] = f2bh(v - bh2f(h));
        }
        return;
    }
    if (blk < 340) {
        int e = (blk - 20) * 256 + t;          // < 81920
        int ty = e / 40960;
        int r  = e - ty * 40960;
        float v = 0.0f; int dst;
        if (r < 16384) {            // WRM2
            int i = r >> 7, j = r & 127;
            if (i < 100 && j < 100) v = W2[ty * 10000 + i * 100 + j];
            dst = ty * TYW + 81920 + r;
        } else if (r < 32768) {     // WRM1
            int r2 = r - 16384; int i = r2 >> 7, j = r2 & 127;
            if (i < 100 && j < 100) v = W1[ty * 10000 + i * 100 + j];
            dst = ty * TYW + 98304 + r2;
        } else {                    // WRM0
            int r2 = r - 32768; int f = r2 >> 7, j = r2 & 127;
            if (f < 50 && j < 100) v = W0[ty * 5000 + f * 100 + j];
            dst = ty * TYW + 114688 + r2;
        }
        wsu[dst] = f2bh(v);
        return;
    }
    // sort: type partition, pad each segment to ATB
    __shared__ int scan[256];
    for (int i = t; i < ORDER_LEN; i += 256) order[i] = -1;
    int tyv[16]; int c0 = 0;
    #pragma unroll
    for (int k = 0; k < 16; ++k) {
        int tt = (itype[t * 16 + k] == 8) ? 1 : 0;
        tyv[k] = tt; c0 += 1 - tt;
    }
    scan[t] = c0;
    __syncthreads();
    for (int off = 1; off < 256; off <<= 1) {
        int v = scan[t];
        int add = (t >= off) ? scan[t - off] : 0;
        __syncthreads();
        scan[t] = v + add;
        __syncthreads();
    }
    int total0 = scan[255];
    int ex0 = scan[t] - c0;
    int ex1 = 16 * t - ex0;
    int pad0 = (total0 + (ATB - 1)) & ~(ATB - 1);
    int p0 = ex0, p1 = pad0 + ex1;
    #pragma unroll
    for (int k = 0; k < 16; ++k) {
        int idx = t * 16 + k;
        if (tyv[k] == 0) order[p0++] = idx; else order[p1++] = idx;
    }
}

// ------------------------------------------------- feat (no atomics)
__global__ __launch_bounds__(128) void feat_kernel(
    const int* __restrict__ itype, const int* __restrict__ nlist,
    const float* __restrict__ dR, float* __restrict__ featp)
{
    const int atom = blockIdx.x;
    const int b = atom >> 10;
    const int t = threadIdx.x;

    __shared__ float rsh[Mn];
    __shared__ float csh[Mn];
    __shared__ int   tsh[Mn];

    if (t < Mn) {
        float4 qv = ((const float4*)dR)[(size_t)atom * Mn + t];
        float r = qv.x;
        int v = nlist[(size_t)atom * Mn + t];
        int tt = -1;
        if (v > 0) tt = (itype[b * Nn + (v - 1)] == 8) ? 1 : 0;
        if (!(r < 6.0f && r > 0.0f)) tt = -1;
        rsh[t] = r;
        csh[t] = 0.5f * __cosf(PIc * r) + 0.5f;
        tsh[t] = tt;
    }
    __syncthreads();

    if (t < 64) {
        float acc = 0.0f;
        if (t < FEAT) {
            const int tt = t / NB;
            const int k  = t - tt * NB;
            const float rk = 0.5f + k * RSTEP;
            for (int m = 0; m < Mn; ++m) {
                if (tsh[m] == tt) {
                    float d = rsh[m] - rk;
                    acc += __expf(-d * d) * csh[m];
                }
            }
        }
        featp[(size_t)atom * 64 + t] = acc;
    }
}

// ----------------------------------------------------------------- mlp ----
// 256 thr = 4 waves, 8 type-pure atoms (16-row tile, rows 8-15 pad).
// Each wave owns 2 n-tiles (vs 4 before): half the per-wave phase work,
// double the waves -> 8 waves/CU for cross-wave latency hiding.
#define GEMMG(ABUF, WH, WL, NKT, RW, NS, NTB, HASLO)                          \
    { bf16x8 afr_[4]; bf16x8 bhr_[4][2]; bf16x8 blr_[4][2];                   \
      _Pragma("unroll")                                                       \
      for (int kt = 0; kt < (NKT); ++kt) {                                    \
        int gk = kt * 4 + q;                                                  \
        afr_[kt] = *(const bf16x8*)&aA[ABUF][(c << 7) | ((gk ^ (c & 7)) << 3)]; \
        _Pragma("unroll")                                                     \
        for (int s2 = 0; s2 < (NS); ++s2) {                                   \
            int jj = c + 16 * ((NTB) + s2);                                   \
            int boff = jj * (RW) + kt * 32 + q * 8;                           \
            bhr_[kt][s2] = *(const bf16x8*)((WH) + boff);                     \
            if (HASLO) blr_[kt][s2] = *(const bf16x8*)((WL) + boff);          \
        } }                                                                   \
      _Pragma("unroll")                                                       \
      for (int kt = 0; kt < (NKT); ++kt) {                                    \
        _Pragma("unroll")                                                     \
        for (int s2 = 0; s2 < (NS); ++s2) {                                   \
            acc[s2] = __builtin_amdgcn_mfma_f32_16x16x32_bf16(afr_[kt], bhr_[kt][s2], acc[s2], 0, 0, 0); \
            if (HASLO)                                                        \
              accl[s2] = __builtin_amdgcn_mfma_f32_16x16x32_bf16(afr_[kt], blr_[kt][s2], accl[s2], 0, 0, 0); \
        } } }

#define ZACC() { _Pragma("unroll") for (int n = 0; n < 2; ++n) { acc[n] = (f32x4){0,0,0,0}; accl[n] = (f32x4){0,0,0,0}; } }

#define WRACT(BUF, J, A, X)                                                   \
    aA[BUF][((A) << 7) | ((((J) >> 3) ^ ((A) & 7)) << 3) | ((J) & 7)] = f2bh(X)

__global__ __launch_bounds__(256) void mlp_kernel(
    const float* __restrict__ featp, const int* __restrict__ itype,
    const int* __restrict__ order, const unsigned short* __restrict__ wsu,
    const float* __restrict__ B0, const float* __restrict__ B1,
    const float* __restrict__ B2, const float* __restrict__ W3,
    const float* __restrict__ B3,
    float* __restrict__ Ei, float* __restrict__ dE)
{
    const int t = threadIdx.x;
    const int w = t >> 6;
    const int lane = t & 63;
    const int c = lane & 15, q = lane >> 4;

    __shared__ unsigned short aA[2][2048];      // 16x128 bf16, pingpong (8KB)
    __shared__ float fshf[16][52];
    __shared__ float dx1s[16][112];
    __shared__ float biasS[4][128];
    __shared__ float eip[4][16];
    __shared__ int aid[16];

    if (t < 16) aid[t] = (t < ATB) ? order[blockIdx.x * ATB + t] : -1;
    __syncthreads();
    int first = -1;
    #pragma unroll
    for (int a = 0; a < ATB; ++a) { int v = aid[a]; if (first < 0 && v >= 0) first = v; }
    if (first < 0) return;
    const int ty = (itype[first] == 8) ? 1 : 0;
    const unsigned short* wb = wsu + (size_t)ty * TYW;

    // stage feats (rows 0-15, zero pad) + biases
    if (t < 128) {
        const int srow = t >> 3, sg = t & 7;
        int v = aid[srow];
        float4 fa = {0,0,0,0}, fb = {0,0,0,0};
        if (v >= 0) {
            const float4* fp = (const float4*)(featp + (size_t)v * 64 + sg * 8);
            fa = fp[0]; fb = fp[1];
        }
        U16x8 pk;
        pk.u[0]=f2bh(fa.x); pk.u[1]=f2bh(fa.y); pk.u[2]=f2bh(fa.z); pk.u[3]=f2bh(fa.w);
        pk.u[4]=f2bh(fb.x); pk.u[5]=f2bh(fb.y); pk.u[6]=f2bh(fb.z); pk.u[7]=f2bh(fb.w);
        *(uint4*)&aA[0][(srow << 7) | ((sg ^ (srow & 7)) << 3)] = pk.q;
        int cbase = sg * 8;
        if (cbase < 52) {
            float vals[8] = {fa.x,fa.y,fa.z,fa.w,fb.x,fb.y,fb.z,fb.w};
            #pragma unroll
            for (int j7 = 0; j7 < 8; ++j7)
                if (cbase + j7 < 52) fshf[srow][cbase + j7] = vals[j7];
        }
    }
    for (int idx = t; idx < 512; idx += 256) {
        int row = idx >> 7, col = idx & 127;
        const float* s = (row == 0) ? B0 : (row == 1) ? B1 : (row == 2) ? B2 : W3;
        biasS[row][col] = (col < 100) ? s[ty * 100 + col] : 0.0f;
    }
    __syncthreads();

    f32x4 acc[2], accl[2];
    float xr[2][4], h0r[2][4], h1r[2][4], h2r[2][4], dxr[2][4];

    // ---- P0: L0 fwd (A=aA0 feat, W=WT0 hi+lo, K=64) -> x1 in aA1 ----
    ZACC();
    GEMMG(0, wb + 0, wb + 8192, 2, 64, 2, 2 * w, 1);
    #pragma unroll
    for (int s = 0; s < 2; ++s) {
        int j = c + 16 * (2 * w + s);
        float bj = biasS[0][j];
        #pragma unroll
        for (int r = 0; r < 4; ++r) {
            int a = q * 4 + r;
            float z = acc[s][r] + accl[s][r] + bj;
            float h = 0.f, x = 0.f;
            if (j < 100) { h = fast_tanh(z); x = h + fshf[a][(j < 50) ? j : j - 50]; }
            h0r[s][r] = h; xr[s][r] = x;
            WRACT(1, j, a, x);
        }
    }
    __syncthreads();

    // ---- P1: L1 fwd (A=aA1, W=WT1 hi+lo) -> x2 in aA0 ----
    ZACC();
    GEMMG(1, wb + 16384, wb + 32768, 4, 128, 2, 2 * w, 1);
    #pragma unroll
    for (int s = 0; s < 2; ++s) {
        int j = c + 16 * (2 * w + s);
        float bj = biasS[1][j];
        #pragma unroll
        for (int r = 0; r < 4; ++r) {
            int a = q * 4 + r;
            float z = acc[s][r] + accl[s][r] + bj;
            float h = (j < 100) ? fast_tanh(z) : 0.f;
            float x = (j < 100) ? (h + xr[s][r]) : 0.f;
            h1r[s][r] = h; xr[s][r] = x;
            WRACT(0, j, a, x);
        }
    }
    __syncthreads();

    // ---- P2: L2 fwd (A=aA0, W=WT2 hi+lo) -> Ei, dz2 in aA1 ----
    ZACC();
    GEMMG(0, wb + 49152, wb + 65536, 4, 128, 2, 2 * w, 1);
    #pragma unroll
    for (int s = 0; s < 2; ++s) {
        int j = c + 16 * (2 * w + s);
        float bj = biasS[2][j];
        #pragma unroll
        for (int r = 0; r < 4; ++r) {
            float z = acc[s][r] + accl[s][r] + bj;
            float h = (j < 100) ? fast_tanh(z) : 0.f;
            h2r[s][r] = h;
            xr[s][r] = (j < 100) ? (h + xr[s][r]) : 0.f;   // x3
        }
    }
    {
        float p4v[4] = {0,0,0,0};
        #pragma unroll
        for (int s = 0; s < 2; ++s) {
            int j = c + 16 * (2 * w + s);
            float wv = biasS[3][j];
            #pragma unroll
            for (int r = 0; r < 4; ++r) p4v[r] += xr[s][r] * wv;
        }
        #pragma unroll
        for (int off = 1; off < 16; off <<= 1) {
            #pragma unroll
            for (int r = 0; r < 4; ++r) p4v[r] += __shfl_xor(p4v[r], off);
        }
        if (c == 0) {
            #pragma unroll
            for (int r = 0; r < 4; ++r) eip[w][q * 4 + r] = p4v[r];
        }
        #pragma unroll
        for (int s = 0; s < 2; ++s) {
            int j = c + 16 * (2 * w + s);
            float w3j = biasS[3][j];
            #pragma unroll
            for (int r = 0; r < 4; ++r) {
                int a = q * 4 + r;
                float d = w3j * (1.0f - h2r[s][r] * h2r[s][r]);
                WRACT(1, j, a, d);
            }
        }
    }
    __syncthreads();
    if (t < ATB) {
        int v = aid[t];
        if (v >= 0) Ei[v] = eip[0][t] + eip[1][t] + eip[2][t] + eip[3][t] + B3[ty];
    }

    // ---- P3: bwd2 (A=aA1 dz2, W=WRM2 hi) -> dz1 in aA0 ----
    ZACC();
    GEMMG(1, wb + 81920, wb, 4, 128, 2, 2 * w, 0);
    #pragma unroll
    for (int s = 0; s < 2; ++s) {
        int i = c + 16 * (2 * w + s);
        float w3i = biasS[3][i];
        #pragma unroll
        for (int r = 0; r < 4; ++r) {
            int a = q * 4 + r;
            float dx2 = acc[s][r] + w3i;
            dxr[s][r] = dx2;
            float d = dx2 * (1.0f - h1r[s][r] * h1r[s][r]);   // dz1
            WRACT(0, i, a, d);
        }
    }
    __syncthreads();

    // ---- P4: bwd1 (A=aA0 dz1, W=WRM1 hi) -> dz0 in aA1, dx1s ----
    ZACC();
    GEMMG(0, wb + 98304, wb, 4, 128, 2, 2 * w, 0);
    #pragma unroll
    for (int s = 0; s < 2; ++s) {
        int i = c + 16 * (2 * w + s);
        #pragma unroll
        for (int r = 0; r < 4; ++r) {
            int a = q * 4 + r;
            float dx1 = dxr[s][r] + acc[s][r];
            if (i < 112) dx1s[a][i] = dx1;
            float d = dx1 * (1.0f - h0r[s][r] * h0r[s][r]);   // dz0
            WRACT(1, i, a, d);
        }
    }
    __syncthreads();

    // ---- P5: bwd0 (A=aA1 dz0, W=WRM0 hi, N=64, 1 tile/wave) -> dE ----
    ZACC();
    GEMMG(1, wb + 114688, wb, 4, 128, 1, w, 0);
    {
        int f = c + 16 * w;
        if (f < 50) {
            #pragma unroll
            for (int r = 0; r < 4; ++r) {
                int a = q * 4 + r;
                int v = aid[a];
                if (v >= 0) dE[(size_t)v * FEAT + f] = acc[0][r] + dx1s[a][f] + dx1s[a][f + 50];
            }
        }
    }
}

// --------------------------------------------------------------- force ----
__global__ __launch_bounds__(FTHREADS) void force_kernel(
    const int* __restrict__ itype, const int* __restrict__ nlist,
    const float* __restrict__ dR, const float* __restrict__ dE,
    float* __restrict__ partial)
{
    const int blk = blockIdx.x;
    const int b = blk / GPB;
    const int g = blk - b * GPB;
    const int t = threadIdx.x;

    __shared__ float acc[(Nn + 1) * 3];
    __shared__ float desh[CPG][FEAT];

    for (int idx = t; idx < (Nn + 1) * 3; idx += FTHREADS) acc[idx] = 0.0f;
    for (int idx = t; idx < CPG * FEAT; idx += FTHREADS)
        ((float*)desh)[idx] = dE[((size_t)(b * Nn) + g * CPG) * FEAT + idx];
    __syncthreads();

    for (int p = t; p < CPG * Mn; p += FTHREADS) {
        int cc = p / Mn, m = p - cc * Mn;
        int n = g * CPG + cc;
        size_t pair = (size_t)(b * Nn + n) * Mn + m;
        float4 qv = ((const float4*)dR)[pair];
        int v = nlist[pair];
        if (v > 0) {
            float r = qv.x;
            if (r > 0.0f && r < 6.0f) {
                int tt = (itype[b * Nn + v - 1] == 8) ? 1 : 0;
                float cw  = 0.5f * __cosf(PIc * r) + 0.5f;
                float dcw = -0.5f * PIc * __sinf(PIc * r);
                float s = 0.0f;
                const float* de = &desh[cc][tt * NB];
                #pragma unroll
                for (int k = 0; k < NB; ++k) {
                    float d = r - (0.5f + k * RSTEP);
                    float e = __expf(-d * d);
                    s += de[k] * e * __builtin_fmaf(-2.0f * cw, d, dcw);
                }
                float inv = 1.0f / r;
                float fx = s * qv.y * inv, fy = s * qv.z * inv, fz = s * qv.w * inv;
                atomicAdd(&acc[v * 3 + 0], fx);
                atomicAdd(&acc[v * 3 + 1], fy);
                atomicAdd(&acc[v * 3 + 2], fz);
                atomicAdd(&acc[(n + 1) * 3 + 0], -fx);
                atomicAdd(&acc[(n + 1) * 3 + 1], -fy);
                atomicAdd(&acc[(n + 1) * 3 + 2], -fz);
            }
        }
    }
    __syncthreads();

    float* pout = partial + (size_t)blk * ((Nn + 1) * 3);
    for (int idx = t; idx < (Nn + 1) * 3; idx += FTHREADS) pout[idx] = acc[idx];
}

// ----------------------------------------------------- freduce (+etot) ----
__global__ __launch_bounds__(256) void freduce_kernel(
    const float* __restrict__ partial, const float* __restrict__ Ei,
    float* __restrict__ Force, float* __restrict__ Etot)
{
    if (blockIdx.x == 48) {   // etot
        const int t = threadIdx.x;
        __shared__ float red[256];
        for (int b = 0; b < Bn; ++b) {
            float s = 0.0f;
            for (int i = t; i < Nn; i += 256) s += Ei[b * Nn + i];
            red[t] = s;
            __syncthreads();
            for (int st = 128; st > 0; st >>= 1) {
                if (t < st) red[t] += red[t + st];
                __syncthreads();
            }
            if (t == 0) Etot[b] = red[0];
            __syncthreads();
        }
        return;
    }
    int idx = blockIdx.x * 256 + threadIdx.x;
    if (idx >= Bn * Nn * 3) return;
    int b = idx / (Nn * 3);
    int r = idx - b * (Nn * 3);
    int i = r / 3, ch = r - i * 3;
    float s = 0.0f;
    for (int g = 0; g < GPB; ++g)
        s += partial[((size_t)(b * GPB + g)) * ((Nn + 1) * 3) + (size_t)(i + 1) * 3 + ch];
    Force[idx] = s;
}

// -------------------------------------------------------------- launch ----
extern "C" void kernel_launch(void* const* d_in, const int* in_sizes, int n_in,
                              void* d_out, int out_size, void* d_ws, size_t ws_size,
                              hipStream_t stream)
{
    const int*   itype = (const int*)d_in[0];
    const int*   nlist = (const int*)d_in[1];
    const float* dR    = (const float*)d_in[2];
    const float* W0 = (const float*)d_in[3];  const float* B0 = (const float*)d_in[4];
    const float* W1 = (const float*)d_in[5];  const float* B1 = (const float*)d_in[6];
    const float* W2 = (const float*)d_in[7];  const float* B2 = (const float*)d_in[8];
    const float* W3 = (const float*)d_in[9];  const float* B3 = (const float*)d_in[10];

    float* out   = (float*)d_out;
    float* Etot  = out;                    // [B,1]
    float* Ei    = out + Bn;               // [B,N,1]
    float* Force = out + Bn + Bn * Nn;     // [B,N,3]

    float* featp   = (float*)d_ws;                              // NATOMS*64 f32
    float* dEp     = featp + (size_t)NATOMS * 64;               // NATOMS*50 f32
    float* partial = dEp + (size_t)NATOMS * FEAT;               // Bn*GPB*(Nn+1)*3
    int*   order   = (int*)(partial + (size_t)Bn * GPB * (Nn + 1) * 3);
    unsigned short* wsu = (unsigned short*)(order + ORDER_LEN); // 2*TYW ushorts

    wprep_kernel  <<<341, 256, 0, stream>>>(itype, W0, W1, W2, order, wsu);
    feat_kernel   <<<NATOMS, 128, 0, stream>>>(itype, nlist, dR, featp);
    mlp_kernel    <<<MLP_BLOCKS, 256, 0, stream>>>(featp, itype, order, wsu,
                                                   B0, B1, B2, W3, B3, Ei, dEp);
    force_kernel  <<<Bn * GPB, FTHREADS, 0, stream>>>(itype, nlist, dR, dEp, partial);
    freduce_kernel<<<49, 256, 0, stream>>>(partial, Ei, Force, Etot);
}

// Round 11
// 59.650 us; speedup vs baseline: 2.1437x; 1.1914x over previous
//
#include <hip/hip_runtime.h>

#define Bn   4
#define Nn   1024
#define Mn   100
#define NB   25
#define FEAT 50
#define PIc  3.1415926f
#define RSTEP (5.5f / 24.0f)

#define ATB  16                         // atoms per MLP block (all real now)
#define NATOMS (Bn * Nn)
#define ORDER_LEN (NATOMS + ATB)        // 4112
#define MLP_BLOCKS (ORDER_LEN / ATB)    // 257
#define TYW  122880                     // ushorts per type in wsu

#define GPB  64
#define CPG  16
#define FTHREADS 512

typedef __attribute__((ext_vector_type(8))) short bf16x8;
typedef __attribute__((ext_vector_type(4))) float f32x4;

union U16x8 { unsigned short u[8]; bf16x8 v; uint4 q; };

__device__ __forceinline__ unsigned short f2bh(float x) {
    union { float f; unsigned u; } v; v.f = x;
    unsigned r = v.u + 0x7fffu + ((v.u >> 16) & 1u);
    return (unsigned short)(r >> 16);
}
__device__ __forceinline__ float bh2f(unsigned short h) {
    union { unsigned u; float f; } v; v.u = ((unsigned)h) << 16; return v.f;
}
__device__ __forceinline__ float fast_tanh(float x) {
    float ax = fabsf(x);
    float t  = __expf(-2.0f * ax);
    float r  = (1.0f - t) * __builtin_amdgcn_rcpf(1.0f + t);
    return copysignf(r, x);
}

// wsu layout per type (ushort offsets):
// 0      WT0h [128j][64k]   8192   (fwd L0 hi)     8192 WT0l
// 16384  WT1h [128j][128k] 16384   32768 WT1l
// 49152  WT2h             16384    65536 WT2l
// 81920  WRM2 [128i][128j] 16384   (bwd hi only)
// 98304  WRM1             16384
// 114688 WRM0 [64f][128j]  8192

// ------------------------------------------------ wprep: transpose+copy+sort
__global__ __launch_bounds__(256) void wprep_kernel(
    const int* __restrict__ itype,
    const float* __restrict__ W0, const float* __restrict__ W1,
    const float* __restrict__ W2,
    int* __restrict__ order, unsigned short* __restrict__ wsu)
{
    const int blk = blockIdx.x;
    const int t = threadIdx.x;

    if (blk < 20) {
        __shared__ float tile[64][65];
        int ty = blk / 10, m = blk - ty * 10;
        int mat, jt, kt;
        if (m < 2)      { mat = 0; jt = m;            kt = 0; }
        else if (m < 6) { mat = 1; jt = (m - 2) >> 1; kt = (m - 2) & 1; }
        else            { mat = 2; jt = (m - 6) >> 1; kt = (m - 6) & 1; }
        const float* src = (mat == 0) ? W0 + ty * 5000
                          : (mat == 1) ? W1 + ty * 10000 : W2 + ty * 10000;
        const int Krows = (mat == 0) ? 50 : 100;
        const int Ck    = (mat == 0) ? 64 : 128;
        const int dH = ty * TYW + ((mat == 0) ? 0 : (mat == 1) ? 16384 : 49152);
        const int dL = dH + ((mat == 0) ? 8192 : 16384);
        const int j0 = jt * 64, k0 = kt * 64;
        const int rr0 = t >> 6, l = t & 63;
        #pragma unroll
        for (int i = 0; i < 16; ++i) {
            int rr = rr0 + 4 * i;
            int k = k0 + rr, j = j0 + l;
            tile[rr][l] = (k < Krows && j < 100) ? src[k * 100 + j] : 0.0f;
        }
        __syncthreads();
        #pragma unroll
        for (int i = 0; i < 16; ++i) {
            int jj = rr0 + 4 * i;
            float v = tile[l][jj];
            unsigned short h = f2bh(v);
            wsu[dH + (j0 + jj) * Ck + k0 + l] = h;
            wsu[dL + (j0 + jj) * Ck + k0 + l] = f2bh(v - bh2f(h));
        }
        return;
    }
    if (blk < 340) {
        int e = (blk - 20) * 256 + t;          // < 81920
        int ty = e / 40960;
        int r  = e - ty * 40960;
        float v = 0.0f; int dst;
        if (r < 16384) {            // WRM2
            int i = r >> 7, j = r & 127;
            if (i < 100 && j < 100) v = W2[ty * 10000 + i * 100 + j];
            dst = ty * TYW + 81920 + r;
        } else if (r < 32768) {     // WRM1
            int r2 = r - 16384; int i = r2 >> 7, j = r2 & 127;
            if (i < 100 && j < 100) v = W1[ty * 10000 + i * 100 + j];
            dst = ty * TYW + 98304 + r2;
        } else {                    // WRM0
            int r2 = r - 32768; int f = r2 >> 7, j = r2 & 127;
            if (f < 50 && j < 100) v = W0[ty * 5000 + f * 100 + j];
            dst = ty * TYW + 114688 + r2;
        }
        wsu[dst] = f2bh(v);
        return;
    }
    // sort: type partition, pad each segment to ATB
    __shared__ int scan[256];
    for (int i = t; i < ORDER_LEN; i += 256) order[i] = -1;
    int tyv[16]; int c0 = 0;
    #pragma unroll
    for (int k = 0; k < 16; ++k) {
        int tt = (itype[t * 16 + k] == 8) ? 1 : 0;
        tyv[k] = tt; c0 += 1 - tt;
    }
    scan[t] = c0;
    __syncthreads();
    for (int off = 1; off < 256; off <<= 1) {
        int v = scan[t];
        int add = (t >= off) ? scan[t - off] : 0;
        __syncthreads();
        scan[t] = v + add;
        __syncthreads();
    }
    int total0 = scan[255];
    int ex0 = scan[t] - c0;
    int ex1 = 16 * t - ex0;
    int pad0 = (total0 + (ATB - 1)) & ~(ATB - 1);
    int p0 = ex0, p1 = pad0 + ex1;
    #pragma unroll
    for (int k = 0; k < 16; ++k) {
        int idx = t * 16 + k;
        if (tyv[k] == 0) order[p0++] = idx; else order[p1++] = idx;
    }
}

// ------------------------- feat: packed float2 (r, +/-cw), b128 reads, 2 waves
__global__ __launch_bounds__(128) void feat_kernel(
    const int* __restrict__ itype, const int* __restrict__ nlist,
    const float* __restrict__ dR, float* __restrict__ featp)
{
    const int atom = blockIdx.x;
    const int b = atom >> 10;
    const int t = threadIdx.x;

    __shared__ float4 rc4[50];          // 100 x float2 (r, cw_signed)
    __shared__ float partial[64];

    if (t < Mn) {
        float4 qv = ((const float4*)dR)[(size_t)atom * Mn + t];
        float r = qv.x;
        int v = nlist[(size_t)atom * Mn + t];
        float cws = 0.0f;
        if (v > 0 && r > 0.0f && r < 6.0f) {
            float cw = 0.5f * __cosf(PIc * r) + 0.5f;
            cws = (itype[b * Nn + (v - 1)] == 8) ? -cw : cw;
        }
        ((float2*)rc4)[t] = make_float2(r, cws);
    }
    __syncthreads();

    const int w = t >> 6, l = t & 63;
    const int tt = l / NB;
    const float rk = 0.5f + (l - tt * NB) * RSTEP;
    float acc = 0.0f;
    #pragma unroll
    for (int i = 0; i < 25; ++i) {
        float4 pr = rc4[w * 25 + i];    // (r0, c0s, r1, c1s)
        float d0 = pr.x - rk, d1 = pr.z - rk;
        float c0 = tt ? fmaxf(-pr.y, 0.0f) : fmaxf(pr.y, 0.0f);
        float c1 = tt ? fmaxf(-pr.w, 0.0f) : fmaxf(pr.w, 0.0f);
        acc += __expf(-d0 * d0) * c0 + __expf(-d1 * d1) * c1;
    }
    if (w == 1) partial[l] = acc;
    __syncthreads();
    if (w == 0) {
        float tot = (l < FEAT) ? (acc + partial[l]) : 0.0f;
        featp[(size_t)atom * 64 + l] = tot;
    }
}

// ----------------------------------------------------------------- mlp ----
// 512 thr = 8 waves, 16 REAL type-pure atoms (full 16-row MFMA tile).
// Each wave owns ONE 16-col n-tile. B double-buffered in registers with
// cross-phase prefetch: phase p issues phase p+1's loads before its epilogue.
#define ISSUE(RH, RL, OFFU, OFFL, RW, NKT, HASLO, COND)                       \
    if (COND) {                                                               \
        int jj_ = c + 16 * w;                                                 \
        _Pragma("unroll")                                                     \
        for (int kt = 0; kt < (NKT); ++kt) {                                  \
            int boff_ = jj_ * (RW) + kt * 32 + q * 8;                         \
            RH[kt] = *(const bf16x8*)(wb + (OFFU) + boff_);                   \
            if (HASLO) RL[kt] = *(const bf16x8*)(wb + (OFFL) + boff_);        \
        }                                                                     \
    }

#define GEMM_R(ABUF, RH, RL, NKT, HASLO)                                      \
    {                                                                         \
        acc = (f32x4){0,0,0,0}; accl = (f32x4){0,0,0,0};                      \
        _Pragma("unroll")                                                     \
        for (int kt = 0; kt < (NKT); ++kt) {                                  \
            int gk = kt * 4 + q;                                              \
            bf16x8 af = *(const bf16x8*)&aA[ABUF][(c << 7) | ((gk ^ (c & 7)) << 3)]; \
            acc = __builtin_amdgcn_mfma_f32_16x16x32_bf16(af, RH[kt], acc, 0, 0, 0); \
            if (HASLO) accl = __builtin_amdgcn_mfma_f32_16x16x32_bf16(af, RL[kt], accl, 0, 0, 0); \
        }                                                                     \
    }

#define WRACT(BUF, J, A, X)                                                   \
    aA[BUF][((A) << 7) | ((((J) >> 3) ^ ((A) & 7)) << 3) | ((J) & 7)] = f2bh(X)

__global__ __launch_bounds__(512) void mlp_kernel(
    const float* __restrict__ featp, const int* __restrict__ itype,
    const int* __restrict__ order, const unsigned short* __restrict__ wsu,
    const float* __restrict__ B0, const float* __restrict__ B1,
    const float* __restrict__ B2, const float* __restrict__ W3,
    const float* __restrict__ B3,
    float* __restrict__ Ei, float* __restrict__ dE)
{
    const int t = threadIdx.x;
    const int w = t >> 6;               // 0..7 : n-tile owner
    const int lane = t & 63;
    const int c = lane & 15, q = lane >> 4;

    __shared__ unsigned short aA[2][2048];      // 16x128 bf16, pingpong (8KB)
    __shared__ float fshf[16][52];
    __shared__ float dx1s[16][112];
    __shared__ float biasS[4][128];
    __shared__ float eip[8][16];
    __shared__ int aid[16];

    if (t < 16) aid[t] = order[blockIdx.x * ATB + t];
    __syncthreads();
    int first = -1;
    #pragma unroll
    for (int a = 0; a < ATB; ++a) { int v = aid[a]; if (first < 0 && v >= 0) first = v; }
    if (first < 0) return;
    const int ty = (itype[first] == 8) ? 1 : 0;
    const unsigned short* wb = wsu + (size_t)ty * TYW;

    bf16x8 bh0[4], bl0[4], bh1[4], bl1[4];
    f32x4 acc, accl;
    float xr[4], h0r[4], h1r[4], h2r[4], dxr[4];

    // ---- prologue: issue WT0 loads; stage feats + biases ----
    ISSUE(bh0, bl0, 0, 8192, 64, 2, 1, true);
    if (t < 128) {
        const int srow = t >> 3, sg = t & 7;
        int v = aid[srow];
        float4 fa = {0,0,0,0}, fb = {0,0,0,0};
        if (v >= 0) {
            const float4* fp = (const float4*)(featp + (size_t)v * 64 + sg * 8);
            fa = fp[0]; fb = fp[1];
        }
        U16x8 pk;
        pk.u[0]=f2bh(fa.x); pk.u[1]=f2bh(fa.y); pk.u[2]=f2bh(fa.z); pk.u[3]=f2bh(fa.w);
        pk.u[4]=f2bh(fb.x); pk.u[5]=f2bh(fb.y); pk.u[6]=f2bh(fb.z); pk.u[7]=f2bh(fb.w);
        *(uint4*)&aA[0][(srow << 7) | ((sg ^ (srow & 7)) << 3)] = pk.q;
        int cbase = sg * 8;
        if (cbase < 52) {
            float vals[8] = {fa.x,fa.y,fa.z,fa.w,fb.x,fb.y,fb.z,fb.w};
            #pragma unroll
            for (int j7 = 0; j7 < 8; ++j7)
                if (cbase + j7 < 52) fshf[srow][cbase + j7] = vals[j7];
        }
    }
    if (t < 512) {
        int row = t >> 7, col = t & 127;
        const float* s = (row == 0) ? B0 : (row == 1) ? B1 : (row == 2) ? B2 : W3;
        biasS[row][col] = (col < 100) ? s[ty * 100 + col] : 0.0f;
    }
    __syncthreads();

    // ---- P0: L0 fwd (buf0=WT0 h+l, A=aA0 feat) -> x1 in aA1 ----
    ISSUE(bh1, bl1, 16384, 32768, 128, 4, 1, true);     // prefetch WT1
    GEMM_R(0, bh0, bl0, 2, 1);
    {
        int j = c + 16 * w;
        float bj = biasS[0][j];
        #pragma unroll
        for (int r = 0; r < 4; ++r) {
            int a = q * 4 + r;
            float z = acc[r] + accl[r] + bj;
            float h = 0.f, x = 0.f;
            if (j < 100) { h = fast_tanh(z); x = h + fshf[a][(j < 50) ? j : j - 50]; }
            h0r[r] = h; xr[r] = x;
            WRACT(1, j, a, x);
        }
    }
    __syncthreads();

    // ---- P1: L1 fwd (buf1=WT1, A=aA1) -> x2 in aA0 ----
    ISSUE(bh0, bl0, 49152, 65536, 128, 4, 1, true);     // prefetch WT2
    GEMM_R(1, bh1, bl1, 4, 1);
    {
        int j = c + 16 * w;
        float bj = biasS[1][j];
        #pragma unroll
        for (int r = 0; r < 4; ++r) {
            int a = q * 4 + r;
            float z = acc[r] + accl[r] + bj;
            float h = (j < 100) ? fast_tanh(z) : 0.f;
            float x = (j < 100) ? (h + xr[r]) : 0.f;
            h1r[r] = h; xr[r] = x;
            WRACT(0, j, a, x);
        }
    }
    __syncthreads();

    // ---- P2: L2 fwd (buf0=WT2, A=aA0) -> Ei partials, dz2 in aA1 ----
    ISSUE(bh1, bl1, 81920, 0, 128, 4, 0, true);         // prefetch WRM2 (hi)
    GEMM_R(0, bh0, bl0, 4, 1);
    {
        int j = c + 16 * w;
        float bj = biasS[2][j];
        float wv = biasS[3][j];
        float p4v[4];
        #pragma unroll
        for (int r = 0; r < 4; ++r) {
            float z = acc[r] + accl[r] + bj;
            float h = (j < 100) ? fast_tanh(z) : 0.f;
            h2r[r] = h;
            xr[r] = (j < 100) ? (h + xr[r]) : 0.f;      // x3
            p4v[r] = xr[r] * wv;
        }
        #pragma unroll
        for (int off = 1; off < 16; off <<= 1) {
            #pragma unroll
            for (int r = 0; r < 4; ++r) p4v[r] += __shfl_xor(p4v[r], off);
        }
        if (c == 0) {
            #pragma unroll
            for (int r = 0; r < 4; ++r) eip[w][q * 4 + r] = p4v[r];
        }
        #pragma unroll
        for (int r = 0; r < 4; ++r) {
            int a = q * 4 + r;
            float d = wv * (1.0f - h2r[r] * h2r[r]);    // dz2
            WRACT(1, j, a, d);
        }
    }
    __syncthreads();
    if (t < 16) {
        int v = aid[t];
        if (v >= 0) {
            float e = B3[ty];
            #pragma unroll
            for (int ww = 0; ww < 8; ++ww) e += eip[ww][t];
            Ei[v] = e;
        }
    }

    // ---- P3: bwd2 (buf1=WRM2, A=aA1 dz2) -> dz1 in aA0 ----
    ISSUE(bh0, bl0, 98304, 0, 128, 4, 0, true);         // prefetch WRM1
    GEMM_R(1, bh1, bl1, 4, 0);
    {
        int i = c + 16 * w;
        float w3i = biasS[3][i];
        #pragma unroll
        for (int r = 0; r < 4; ++r) {
            int a = q * 4 + r;
            float dx2 = acc[r] + w3i;
            dxr[r] = dx2;
            float d = dx2 * (1.0f - h1r[r] * h1r[r]);   // dz1
            WRACT(0, i, a, d);
        }
    }
    __syncthreads();

    // ---- P4: bwd1 (buf0=WRM1, A=aA0 dz1) -> dz0 in aA1, dx1s ----
    ISSUE(bh1, bl1, 114688, 0, 128, 4, 0, (w < 4));     // prefetch WRM0
    GEMM_R(0, bh0, bl0, 4, 0);
    {
        int i = c + 16 * w;
        #pragma unroll
        for (int r = 0; r < 4; ++r) {
            int a = q * 4 + r;
            float dx1 = dxr[r] + acc[r];
            if (i < 112) dx1s[a][i] = dx1;
            float d = dx1 * (1.0f - h0r[r] * h0r[r]);   // dz0
            WRACT(1, i, a, d);
        }
    }
    __syncthreads();

    // ---- P5: bwd0 (buf1=WRM0, A=aA1 dz0, N=64) -> dE ----
    if (w < 4) {
        GEMM_R(1, bh1, bl1, 4, 0);
        int f = c + 16 * w;
        if (f < 50) {
            #pragma unroll
            for (int r = 0; r < 4; ++r) {
                int a = q * 4 + r;
                int v = aid[a];
                if (v >= 0) dE[(size_t)v * FEAT + f] = acc[r] + dx1s[a][f] + dx1s[a][f + 50];
            }
        }
    }
}

// --------------------------------------------------------------- force ----
__global__ __launch_bounds__(FTHREADS) void force_kernel(
    const int* __restrict__ itype, const int* __restrict__ nlist,
    const float* __restrict__ dR, const float* __restrict__ dE,
    float* __restrict__ partial)
{
    const int blk = blockIdx.x;
    const int b = blk / GPB;
    const int g = blk - b * GPB;
    const int t = threadIdx.x;

    __shared__ float acc[(Nn + 1) * 3];
    __shared__ float desh[CPG][FEAT];

    for (int idx = t; idx < (Nn + 1) * 3; idx += FTHREADS) acc[idx] = 0.0f;
    for (int idx = t; idx < CPG * FEAT; idx += FTHREADS)
        ((float*)desh)[idx] = dE[((size_t)(b * Nn) + g * CPG) * FEAT + idx];
    __syncthreads();

    for (int p = t; p < CPG * Mn; p += FTHREADS) {
        int cc = p / Mn, m = p - cc * Mn;
        int n = g * CPG + cc;
        size_t pair = (size_t)(b * Nn + n) * Mn + m;
        float4 qv = ((const float4*)dR)[pair];
        int v = nlist[pair];
        if (v > 0) {
            float r = qv.x;
            if (r > 0.0f && r < 6.0f) {
                int tt = (itype[b * Nn + v - 1] == 8) ? 1 : 0;
                float cw  = 0.5f * __cosf(PIc * r) + 0.5f;
                float dcw = -0.5f * PIc * __sinf(PIc * r);
                float s = 0.0f;
                const float* de = &desh[cc][tt * NB];
                #pragma unroll
                for (int k = 0; k < NB; ++k) {
                    float d = r - (0.5f + k * RSTEP);
                    float e = __expf(-d * d);
                    s += de[k] * e * __builtin_fmaf(-2.0f * cw, d, dcw);
                }
                float inv = 1.0f / r;
                float fx = s * qv.y * inv, fy = s * qv.z * inv, fz = s * qv.w * inv;
                atomicAdd(&acc[v * 3 + 0], fx);
                atomicAdd(&acc[v * 3 + 1], fy);
                atomicAdd(&acc[v * 3 + 2], fz);
                atomicAdd(&acc[(n + 1) * 3 + 0], -fx);
                atomicAdd(&acc[(n + 1) * 3 + 1], -fy);
                atomicAdd(&acc[(n + 1) * 3 + 2], -fz);
            }
        }
    }
    __syncthreads();

    float* pout = partial + (size_t)blk * ((Nn + 1) * 3);
    for (int idx = t; idx < (Nn + 1) * 3; idx += FTHREADS) pout[idx] = acc[idx];
}

// ----------------------------------------------------- freduce (+etot) ----
__global__ __launch_bounds__(256) void freduce_kernel(
    const float* __restrict__ partial, const float* __restrict__ Ei,
    float* __restrict__ Force, float* __restrict__ Etot)
{
    if (blockIdx.x == 48) {   // etot
        const int t = threadIdx.x;
        __shared__ float red[256];
        for (int b = 0; b < Bn; ++b) {
            float s = 0.0f;
            for (int i = t; i < Nn; i += 256) s += Ei[b * Nn + i];
            red[t] = s;
            __syncthreads();
            for (int st = 128; st > 0; st >>= 1) {
                if (t < st) red[t] += red[t + st];
                __syncthreads();
            }
            if (t == 0) Etot[b] = red[0];
            __syncthreads();
        }
        return;
    }
    int idx = blockIdx.x * 256 + threadIdx.x;
    if (idx >= Bn * Nn * 3) return;
    int b = idx / (Nn * 3);
    int r = idx - b * (Nn * 3);
    int i = r / 3, ch = r - i * 3;
    float s = 0.0f;
    for (int g = 0; g < GPB; ++g)
        s += partial[((size_t)(b * GPB + g)) * ((Nn + 1) * 3) + (size_t)(i + 1) * 3 + ch];
    Force[idx] = s;
}

// -------------------------------------------------------------- launch ----
extern "C" void kernel_launch(void* const* d_in, const int* in_sizes, int n_in,
                              void* d_out, int out_size, void* d_ws, size_t ws_size,
                              hipStream_t stream)
{
    const int*   itype = (const int*)d_in[0];
    const int*   nlist = (const int*)d_in[1];
    const float* dR    = (const float*)d_in[2];
    const float* W0 = (const float*)d_in[3];  const float* B0 = (const float*)d_in[4];
    const float* W1 = (const float*)d_in[5];  const float* B1 = (const float*)d_in[6];
    const float* W2 = (const float*)d_in[7];  const float* B2 = (const float*)d_in[8];
    const float* W3 = (const float*)d_in[9];  const float* B3 = (const float*)d_in[10];

    float* out   = (float*)d_out;
    float* Etot  = out;                    // [B,1]
    float* Ei    = out + Bn;               // [B,N,1]
    float* Force = out + Bn + Bn * Nn;     // [B,N,3]

    float* featp   = (float*)d_ws;                              // NATOMS*64 f32
    float* dEp     = featp + (size_t)NATOMS * 64;               // NATOMS*50 f32
    float* partial = dEp + (size_t)NATOMS * FEAT;               // Bn*GPB*(Nn+1)*3
    int*   order   = (int*)(partial + (size_t)Bn * GPB * (Nn + 1) * 3);
    unsigned short* wsu = (unsigned short*)(order + ORDER_LEN); // 2*TYW ushorts

    wprep_kernel  <<<341, 256, 0, stream>>>(itype, W0, W1, W2, order, wsu);
    feat_kernel   <<<NATOMS, 128, 0, stream>>>(itype, nlist, dR, featp);
    mlp_kernel    <<<MLP_BLOCKS, 512, 0, stream>>>(featp, itype, order, wsu,
                                                   B0, B1, B2, W3, B3, Ei, dEp);
    force_kernel  <<<Bn * GPB, FTHREADS, 0, stream>>>(itype, nlist, dR, dEp, partial);
    freduce_kernel<<<49, 256, 0, stream>>>(partial, Ei, Force, Etot);
}